// Round 10
// baseline (4680.973 us; speedup 1.0000x reference)
//
#include <hip/hip_runtime.h>

#define B_  128
#define S_  256
#define E_  300
#define EP_ 320
#define H_  512
#define G_  2048   // 4*H
#define D1_ 1024   // 2*H
// padded flags: [grp][slot(4)][wave(4)][jb(32)] x 32 u32 (128B line each)
#define FSLOT_ 4
#define FA_WORDS_ (4*FSLOT_*4*32*32)
#define FC_WORDS_ (2*FSLOT_*4*32*32)

typedef _Float16 f16;
typedef __attribute__((ext_vector_type(8))) _Float16 f16x8;
typedef __attribute__((ext_vector_type(4))) float    f32x4;
typedef unsigned long long u64;
typedef unsigned int u32;

__device__ __forceinline__ float sigf(float x){ return 1.f/(1.f + __expf(-x)); }
__device__ __forceinline__ float tanhf_(float x){
  float e = __expf(-2.f*fabsf(x));
  float t = (1.f - e)/(1.f + e);
  return x < 0.f ? -t : t;
}

// Relaxed agent-scope atomics route to the coherence point, bypassing the
// non-coherent per-XCD L2s.
// Ledger (us/step, phaseA): R1 fetch_add 11.0; R2 same-line flags 12.2; R4
// tagged 14.2; R5 batch h-loads 10.35; R7 Wi->LDS + x-reg-prefetch 8.8;
// R8 line-padded write-once flags 8.0. Execution ~0.9 (MfmaUtil 4.4%).
// R9 theory: vmcnt decrements IN ISSUE ORDER -> prefetch loads issued BEFORE
// the poll gate the poll observation (reading the youngest load's result
// requires all older loads to complete). Fix: issue prefetches AFTER the
// h-load batch (younger than hq -> h-GEMM's counted waits skip them; the
// publish vmcnt(0) gives them the MFMA+gates window to land).
__device__ __forceinline__ u64 aload64(const u64* p){
  return __hip_atomic_load((u64*)p, __ATOMIC_RELAXED, __HIP_MEMORY_SCOPE_AGENT);
}
__device__ __forceinline__ u32 aload32(const u32* p){
  return __hip_atomic_load((u32*)p, __ATOMIC_RELAXED, __HIP_MEMORY_SCOPE_AGENT);
}
__device__ __forceinline__ void astore32(u32* p, u32 v){
  __hip_atomic_store(p, v, __ATOMIC_RELAXED, __HIP_MEMORY_SCOPE_AGENT);
}
union H8 { u64 q[2]; f16x8 v; };
union FU { f16 f; unsigned short s; };

// ---------------- setup kernels ----------------

__global__ void k_f32_to_f16(const float* __restrict__ s, f16* __restrict__ d, int n){
  int i = blockIdx.x*blockDim.x + threadIdx.x;
  if (i < n) d[i] = (f16)s[i];
}

__global__ void k_pad_w(const float* __restrict__ s, f16* __restrict__ d, int rows, int ks, int kd){
  int i = blockIdx.x*blockDim.x + threadIdx.x;
  if (i >= rows*kd) return;
  int r = i/kd, k = i - r*kd;
  d[i] = (k < ks) ? (f16)s[(size_t)r*ks + k] : (f16)0.f;
}

__global__ void k_bias(const float* __restrict__ a, const float* __restrict__ b,
                       float* __restrict__ d, int n){
  int i = blockIdx.x*blockDim.x + threadIdx.x;
  if (i < n) d[i] = a[i] + b[i];
}

__global__ void k_len(const float* __restrict__ x, int* __restrict__ len){
  int b = threadIdx.x;
  if (b < B_){
    int v = (int)x[((size_t)b*S_ + (S_-1))*E_];
    len[b] = v > S_ ? S_ : v;
  }
}

__global__ void k_zero(u32* __restrict__ p, int n){
  int i = blockIdx.x*blockDim.x + threadIdx.x;
  if (i < n) p[i] = 0u;
}

// hxA: [dir][parity][B*H], hx1: [parity][B*H]; parity-0 = h0 = 1. cstate = c0 = 1.
__global__ void k_init(f16* hxA, f16* hx1, float* cstate){
  int i = blockIdx.x*blockDim.x + threadIdx.x;
  if (i < B_*H_){
    hxA[i] = (f16)1.f;                // dir0 par0
    hxA[2*B_*H_ + i] = (f16)1.f;      // dir1 par0
    hx1[i] = (f16)1.f;                // par0
    cstate[i] = 1.f;
  }
}

// ---------------- GEMM: C[M,N] = A[M,K] @ B[N,K]^T + bias (f16 in/out, fp32 acc) ----------------

__global__ __launch_bounds__(256) void k_gemm_bt(
    const f16* __restrict__ A, const f16* __restrict__ Bm,
    f16* __restrict__ C, const float* __restrict__ bias,
    int M, int N, int K)
{
  __shared__ f16 As[64*40];
  __shared__ f16 Bs[64*40];
  const int m0 = blockIdx.x*64, n0 = blockIdx.y*64;
  const int tid = threadIdx.x;
  const int w = tid>>6, lane = tid&63, quad = lane>>4, l16 = lane&15;
  const int wm = (w&1)*32, wn = (w>>1)*32;
  const int lr = tid>>2, lc = (tid&3)*8;
  const f16* Ap = A + (size_t)(m0+lr)*K + lc;
  const f16* Bp = Bm + (size_t)(n0+lr)*K + lc;
  f32x4 z4 = {0.f,0.f,0.f,0.f};
  f32x4 acc[2][2] = {{z4,z4},{z4,z4}};
  for (int k0 = 0; k0 < K; k0 += 32){
    *(uint4*)&As[lr*40+lc] = *(const uint4*)(Ap + k0);
    *(uint4*)&Bs[lr*40+lc] = *(const uint4*)(Bp + k0);
    __syncthreads();
    f16x8 a0 = *(const f16x8*)&As[(wm+l16)*40 + quad*8];
    f16x8 a1 = *(const f16x8*)&As[(wm+16+l16)*40 + quad*8];
    f16x8 b0 = *(const f16x8*)&Bs[(wn+l16)*40 + quad*8];
    f16x8 b1 = *(const f16x8*)&Bs[(wn+16+l16)*40 + quad*8];
    acc[0][0] = __builtin_amdgcn_mfma_f32_16x16x32_f16(a0,b0,acc[0][0],0,0,0);
    acc[0][1] = __builtin_amdgcn_mfma_f32_16x16x32_f16(a0,b1,acc[0][1],0,0,0);
    acc[1][0] = __builtin_amdgcn_mfma_f32_16x16x32_f16(a1,b0,acc[1][0],0,0,0);
    acc[1][1] = __builtin_amdgcn_mfma_f32_16x16x32_f16(a1,b1,acc[1][1],0,0,0);
    __syncthreads();
  }
#pragma unroll
  for (int mi = 0; mi < 2; ++mi)
#pragma unroll
    for (int ni = 0; ni < 2; ++ni){
      int col = n0 + wn + ni*16 + l16;
      float bz = bias[col];
#pragma unroll
      for (int r = 0; r < 4; ++r){
        int row = m0 + wm + mi*16 + quad*4 + r;
        C[(size_t)row*N + col] = (f16)(acc[mi][ni][r] + bz);
      }
    }
}

// ---------------- phase A: persistent layer-0 fwd+rev, column-partitioned ----------------
// grid (2,32,2) = 128 blocks, 256 thr. Block: 64 batch rows x 16 hidden x 4 gates.
// LDS: W_hh 64KB + W_ih 40KB (staged once, XOR-swizzled). x_t prefetched one
// step ahead into raw f32 regs; prefetch ISSUED AFTER the h-load batch (R9) so
// the poll observes with zero older vmem outstanding. Sync: per-(wave,jb)
// write-once flag on its own 128B line, value s+1, 4-slot window; producer
// vmcnt(0)+flag; consumer 32-lane gather + ballot. No syncthreads, no RMW.

__global__ __launch_bounds__(256, 1) void k_phaseA(
    const float* __restrict__ x,
    const f16* __restrict__ w0f, const f16* __restrict__ w0r,
    const f16* __restrict__ whf, const f16* __restrict__ whr,
    const float* __restrict__ bs0, const int* __restrict__ len,
    f16* __restrict__ hxA, f16* __restrict__ outcat,
    u32* __restrict__ flagsA)
{
  __shared__ f16 Wh[64*512];   // 64 KB
  __shared__ f16 Wi[64*320];   // 40 KB
  const int half = blockIdx.x, jb = blockIdx.y, dir = blockIdx.z;
  const f16* wih = dir ? w0r : w0f;
  const f16* whh = dir ? whr : whf;
  const float* bias = bs0 + dir*G_;
  f16* hx = hxA + (size_t)dir*(2*B_*H_);
  u32* fbase = flagsA + (size_t)(dir*2 + half)*(FSLOT_*4*32*32);
  const int tid = threadIdx.x;
  const int w = tid>>6, lane = tid&63, quad = lane>>4, l16 = lane&15;
  const int j0 = jb*16;
  const int m0 = half*64 + w*16;       // this wave's 16 batch rows

  for (int u = tid; u < 4096; u += 256){
    int lrr = u>>6, uc = u&63;
    int g = lrr>>4, i = lrr&15;
    *(uint4*)&Wh[lrr*512 + (uc ^ (i&7))*8] =
        *(const uint4*)(whh + ((size_t)(g*H_ + j0 + i))*H_ + uc*8);
  }
  // W_ih slice: 64 rows x 40 chunks of 8 f16; chunk XOR-swizzled per row
  for (int u = tid; u < 2560; u += 256){
    int row = u/40, c = u - row*40;
    int g = row>>4, i = row&15;
    *(uint4*)&Wi[row*320 + (c ^ (i&7))*8] =
        *(const uint4*)(wih + ((size_t)(g*H_ + j0 + i))*EP_ + c*8);
  }
  __syncthreads();

  const int j = j0 + l16;
  float bz[4], hprev[4], cpr[4]; int lm[4];
#pragma unroll
  for (int g = 0; g < 4; ++g) bz[g] = bias[g*H_ + j];
#pragma unroll
  for (int r = 0; r < 4; ++r){ hprev[r] = 1.f; cpr[r] = 1.f; lm[r] = len[m0 + quad*4 + r]; }
  const size_t xrowbase = (size_t)(m0 + l16)*S_;

  // --- cross-step x prefetch state (raw f32; cvt deferred to consumption) ---
  float4 xA[9], xB[9]; float xT[8];
  {
    const int t0 = dir ? (S_-1) : 0;
    const float* xr = x + (xrowbase + t0)*E_;
#pragma unroll
    for (int kb = 0; kb < 9; ++kb){
      xA[kb] = *(const float4*)(xr + kb*32 + quad*8);
      xB[kb] = *(const float4*)(xr + kb*32 + quad*8 + 4);
    }
    int kbase = 288 + quad*8;
#pragma unroll
    for (int e2 = 0; e2 < 8; ++e2)
      xT[e2] = (kbase + e2 < E_) ? xr[kbase + e2] : 0.f;
  }

  for (int s = 0; s < S_; ++s){
    const int t = dir ? (S_-1-s) : s;
    f32x4 z4 = {0.f,0.f,0.f,0.f};
    f32x4 acc[4] = {z4,z4,z4,z4};

    // --- x_t @ Wih^T from prefetched regs + LDS weights (no vmem) ---
#pragma unroll
    for (int kb = 0; kb < 9; ++kb){
      f16x8 a;
      a[0]=(f16)xA[kb].x; a[1]=(f16)xA[kb].y; a[2]=(f16)xA[kb].z; a[3]=(f16)xA[kb].w;
      a[4]=(f16)xB[kb].x; a[5]=(f16)xB[kb].y; a[6]=(f16)xB[kb].z; a[7]=(f16)xB[kb].w;
      int c = (kb*4 + quad) ^ (l16 & 7);
#pragma unroll
      for (int g = 0; g < 4; ++g){
        f16x8 b = *(const f16x8*)&Wi[(g*16+l16)*320 + c*8];
        acc[g] = __builtin_amdgcn_mfma_f32_16x16x32_f16(a, b, acc[g],0,0,0);
      }
    }
    { // K tail 288..319 (x zero-padded in regs; weight pad cols are zero)
      f16x8 a;
#pragma unroll
      for (int e2 = 0; e2 < 8; ++e2) a[e2] = (f16)xT[e2];
      int c = (36 + quad) ^ (l16 & 7);
#pragma unroll
      for (int g = 0; g < 4; ++g){
        f16x8 b = *(const f16x8*)&Wi[(g*16+l16)*320 + c*8];
        acc[g] = __builtin_amdgcn_mfma_f32_16x16x32_f16(a, b, acc[g],0,0,0);
      }
    }

    // --- poll with ZERO older vmem outstanding (first iter observes at
    //     pure round-trip latency; prefetch moved below the h-load issue) ---
    if (s > 0){
      const u32* fp = fbase + ((size_t)((s-1)&(FSLOT_-1))*4 + w)*32*32;
      const u32 expv = (u32)s;
      for (;;){
        u32 v = aload32(fp + (size_t)(lane & 31)*32);
        if (__ballot(v == expv) == ~0ull) break;
      }
      asm volatile("" ::: "memory");   // keep h loads below the poll
    }

    // --- h @ Whh^T (K=512): batch-issue ALL 32 coherence-point loads ---
    const int par = s & 1;
    const u64* hap = (const u64*)(hx + (size_t)par*(B_*H_) + (size_t)(m0 + l16)*H_);
    u64 hq[32];
#pragma unroll
    for (int kb = 0; kb < 16; ++kb){
      hq[2*kb]   = aload64(hap + kb*8 + quad*2);
      hq[2*kb+1] = aload64(hap + kb*8 + quad*2 + 1);
    }

    // --- issue next-step x prefetch AFTER hq (younger -> hq waits skip it;
    //     lands during h-GEMM + gates, drained by the publish vmcnt(0)) ---
    if (s+1 < S_){
      const int tn = dir ? (S_-2-s) : (s+1);
      const float* xr = x + (xrowbase + tn)*E_;
#pragma unroll
      for (int kb = 0; kb < 9; ++kb){
        xA[kb] = *(const float4*)(xr + kb*32 + quad*8);
        xB[kb] = *(const float4*)(xr + kb*32 + quad*8 + 4);
      }
      int kbase = 288 + quad*8;
#pragma unroll
      for (int e2 = 0; e2 < 8; ++e2)
        xT[e2] = (kbase + e2 < E_) ? xr[kbase + e2] : 0.f;
    }

#pragma unroll
    for (int kb = 0; kb < 16; ++kb){
      H8 ha;
      ha.q[0] = hq[2*kb];
      ha.q[1] = hq[2*kb+1];
      int uq = kb*4 + quad;
#pragma unroll
      for (int g = 0; g < 4; ++g){
        f16x8 b = *(const f16x8*)&Wh[(g*16+l16)*512 + ((uq ^ (l16&7)))*8];
        acc[g] = __builtin_amdgcn_mfma_f32_16x16x32_f16(ha.v, b, acc[g],0,0,0);
      }
    }

    // --- gates + state update; publish h (packed 4B, even lanes) ---
    f16* hn = hx + (size_t)(1-par)*(B_*H_);
#pragma unroll
    for (int r = 0; r < 4; ++r){
      int m = m0 + quad*4 + r;
      float zi = acc[0][r] + bz[0];
      float zf = acc[1][r] + bz[1];
      float zg = acc[2][r] + bz[2];
      float zo = acc[3][r] + bz[3];
      float ig = sigf(zi), fg = sigf(zf), gg = tanhf_(zg), og = sigf(zo);
      float cnew = fg*cpr[r] + ig*gg;
      float hnew = og*tanhf_(cnew);
      bool mk = t < lm[r];
      float hsel = mk ? hnew : hprev[r];
      cpr[r] = mk ? cnew : cpr[r];
      hprev[r] = hsel;
      FU cv; cv.f = (f16)hsel;
      int other = __shfl_down((int)cv.s, 1);
      if ((l16 & 1) == 0)
        astore32((u32*)(hn + (size_t)m*H_ + j), (u32)cv.s | ((u32)other << 16));
    }
    // per-wave drain (covers h stores, old-parity reads, and the prefetch),
    // then write-once flag on this (wave,jb)'s private 128B line
    asm volatile("s_waitcnt vmcnt(0)" ::: "memory");
    if (lane == 0)
      astore32(fbase + (((size_t)(s&(FSLOT_-1))*4 + w)*32 + jb)*32, (u32)(s+1));

    // --- deferred outcat stores (off the inter-block critical path) ---
#pragma unroll
    for (int r = 0; r < 4; ++r){
      int m = m0 + quad*4 + r;
      FU cv; cv.f = (f16)hprev[r];
      int other = __shfl_down((int)cv.s, 1);
      if ((l16 & 1) == 0)
        *(u32*)(outcat + ((size_t)t*B_ + m)*D1_ + dir*H_ + j) = (u32)cv.s | ((u32)other << 16);
    }
  }
}

// ---------------- phase C recurrence: layer-1 reverse over one CH-step chunk ----------------
// grid (2,32) = 64 blocks. Same padded-flag scheme; same R9 reorder (Z
// prefetch issued after the h-load batch, not before the poll).

__global__ __launch_bounds__(256, 1) void k_phaseCrec(
    const f16* __restrict__ Z1c, const f16* __restrict__ w1h,
    const int* __restrict__ len,
    f16* __restrict__ hx1, float* __restrict__ cstate, float* __restrict__ h1f,
    u32* __restrict__ flagsC, int s0, int CH)
{
  __shared__ f16 Wh[64*512];   // 64 KB
  const int half = blockIdx.x, jb = blockIdx.y;
  u32* fbase = flagsC + (size_t)half*(FSLOT_*4*32*32);
  const int tid = threadIdx.x;
  const int w = tid>>6, lane = tid&63, quad = lane>>4, l16 = lane&15;
  const int j0 = jb*16;
  const int m0 = half*64 + w*16;

  for (int u = tid; u < 4096; u += 256){
    int lrr = u>>6, uc = u&63;
    int g = lrr>>4, i = lrr&15;
    *(uint4*)&Wh[lrr*512 + (uc ^ (i&7))*8] =
        *(const uint4*)(w1h + ((size_t)(g*H_ + j0 + i))*H_ + uc*8);
  }
  __syncthreads();

  const int j = j0 + l16;
  float hprev[4], cpr[4]; int lm[4];
#pragma unroll
  for (int r = 0; r < 4; ++r){
    int m = m0 + quad*4 + r;
    lm[r] = len[m];
    cpr[r] = cstate[(size_t)m*H_ + j];
    hprev[r] = (float)hx1[(size_t)(s0 & 1)*(B_*H_) + (size_t)m*H_ + j];
  }

  for (int sl = 0; sl < CH; ++sl){
    const int s = s0 + sl;
    const int t = S_-1-s;
    const int zrow = CH-1-sl;

    if (s > 0){
      const u32* fp = fbase + ((size_t)((s-1)&(FSLOT_-1))*4 + w)*32*32;
      const u32 expv = (u32)s;
      for (;;){
        u32 v = aload32(fp + (size_t)(lane & 31)*32);
        if (__ballot(v == expv) == ~0ull) break;
      }
      asm volatile("" ::: "memory");
    }

    // --- h @ Whh1^T (K=512): batch-issue h loads first ---
    const int par = s & 1;
    const u64* hap = (const u64*)(hx1 + (size_t)par*(B_*H_) + (size_t)(m0 + l16)*H_);
    f32x4 z4 = {0.f,0.f,0.f,0.f};
    f32x4 acc[4] = {z4,z4,z4,z4};
    u64 hq[32];
#pragma unroll
    for (int kb = 0; kb < 16; ++kb){
      hq[2*kb]   = aload64(hap + kb*8 + quad*2);
      hq[2*kb+1] = aload64(hap + kb*8 + quad*2 + 1);
    }

    // --- Z prefetch issued after hq (younger; lands during MFMA) ---
    float zv[4][4];
#pragma unroll
    for (int g = 0; g < 4; ++g)
#pragma unroll
      for (int r = 0; r < 4; ++r)
        zv[g][r] = (float)Z1c[((size_t)zrow*B_ + m0 + quad*4 + r)*G_ + g*H_ + j];

#pragma unroll
    for (int kb = 0; kb < 16; ++kb){
      H8 ha;
      ha.q[0] = hq[2*kb];
      ha.q[1] = hq[2*kb+1];
      int uq = kb*4 + quad;
#pragma unroll
      for (int g = 0; g < 4; ++g){
        f16x8 b = *(const f16x8*)&Wh[(g*16+l16)*512 + ((uq ^ (l16&7)))*8];
        acc[g] = __builtin_amdgcn_mfma_f32_16x16x32_f16(ha.v, b, acc[g],0,0,0);
      }
    }

    f16* hn = hx1 + (size_t)(1-par)*(B_*H_);
#pragma unroll
    for (int r = 0; r < 4; ++r){
      int m = m0 + quad*4 + r;
      float zi = acc[0][r] + zv[0][r];
      float zf = acc[1][r] + zv[1][r];
      float zg = acc[2][r] + zv[2][r];
      float zo = acc[3][r] + zv[3][r];
      float ig = sigf(zi), fg = sigf(zf), gg = tanhf_(zg), og = sigf(zo);
      float cnew = fg*cpr[r] + ig*gg;
      float hnew = og*tanhf_(cnew);
      bool mk = t < lm[r];
      float hsel = mk ? hnew : hprev[r];
      cpr[r] = mk ? cnew : cpr[r];
      hprev[r] = hsel;
      FU cv; cv.f = (f16)hsel;
      int other = __shfl_down((int)cv.s, 1);
      if ((l16 & 1) == 0)
        astore32((u32*)(hn + (size_t)m*H_ + j), (u32)cv.s | ((u32)other << 16));
    }
    asm volatile("s_waitcnt vmcnt(0)" ::: "memory");
    if (lane == 0)
      astore32(fbase + (((size_t)(s&(FSLOT_-1))*4 + w)*32 + jb)*32, (u32)(s+1));

    if (t == 0){  // deferred final-state write (consumed by k_final after kernel end)
#pragma unroll
      for (int r = 0; r < 4; ++r)
        h1f[(size_t)(m0 + quad*4 + r)*H_ + j] = hprev[r];
    }
  }

  // persist c across chunk launches (h lives in hx1 parity buffers)
#pragma unroll
  for (int r = 0; r < 4; ++r)
    cstate[(size_t)(m0 + quad*4 + r)*H_ + j] = cpr[r];
}

// ---------------- epilogue: folded FC ----------------

__global__ void k_fold(const float* __restrict__ fc1w, const float* __restrict__ fc1b,
                       const float* __restrict__ fcw,  const float* __restrict__ fcb,
                       float* __restrict__ Mf, float* __restrict__ bf){
  int i = blockIdx.x*blockDim.x + threadIdx.x;
  if (i >= 1024) return;
  int o = i >> 9, h = i & 511;
  float s = 0.f;
  for (int jj = 0; jj < 512; ++jj) s += fcw[o*512 + jj] * fc1w[jj*512 + h];
  Mf[o*512 + h] = s;
  if (h == 0){
    float sb = fcb[o];
    for (int jj = 0; jj < 512; ++jj) sb += fcw[o*512 + jj] * fc1b[jj];
    bf[o] = sb;
  }
}

__global__ void k_final(const float* __restrict__ h1f, const float* __restrict__ Mf,
                        const float* __restrict__ bf, float* __restrict__ out){
  int i = threadIdx.x;
  if (i >= 256) return;
  int b = i >> 1, o = i & 1;
  float s = bf[o];
  const float* hp = h1f + (size_t)b*512;
  const float* mp = Mf + (size_t)o*512;
  for (int h = 0; h < 512; ++h) s += hp[h]*mp[h];
  out[b*2 + o] = s;
}

// ---------------- host ----------------

extern "C" void kernel_launch(void* const* d_in, const int* in_sizes, int n_in,
                              void* d_out, int out_size, void* d_ws, size_t ws_size,
                              hipStream_t stream)
{
  const float* x     = (const float*)d_in[0];
  const float* wih0f = (const float*)d_in[1];
  const float* whh0f = (const float*)d_in[2];
  const float* bih0f = (const float*)d_in[3];
  const float* bhh0f = (const float*)d_in[4];
  const float* wih0r = (const float*)d_in[5];
  const float* whh0r = (const float*)d_in[6];
  const float* bih0r = (const float*)d_in[7];
  const float* bhh0r = (const float*)d_in[8];
  // d_in[9..12] = layer1 forward: dead code (only hT_r of layer1 reaches output)
  const float* wih1r = (const float*)d_in[13];
  const float* whh1r = (const float*)d_in[14];
  const float* bih1r = (const float*)d_in[15];
  const float* bhh1r = (const float*)d_in[16];
  const float* fc1w  = (const float*)d_in[17];
  const float* fc1b  = (const float*)d_in[18];
  const float* fcw   = (const float*)d_in[19];
  const float* fcb   = (const float*)d_in[20];
  float* out = (float*)d_out;

  char* p = (char*)d_ws;
  auto alloc = [&](size_t bytes)->char*{
    char* r = p; p += (bytes + 255) & ~(size_t)255; return r;
  };
  f16* w0fp   = (f16*)alloc((size_t)G_*EP_*2);       // 1.3 MB
  f16* w0rp   = (f16*)alloc((size_t)G_*EP_*2);
  f16* whf    = (f16*)alloc((size_t)G_*H_*2);        // 2 MB
  f16* whr    = (f16*)alloc((size_t)G_*H_*2);
  f16* w1i    = (f16*)alloc((size_t)G_*D1_*2);       // 4 MB
  f16* w1h    = (f16*)alloc((size_t)G_*H_*2);        // 2 MB
  float* bs0  = (float*)alloc((size_t)2*G_*4);
  float* bs1r = (float*)alloc(G_*4);
  int*   len  = (int*)alloc(B_*4);
  f16* outcat = (f16*)alloc((size_t)S_*B_*D1_*2);    // 67 MB
  f16* hxA    = (f16*)alloc((size_t)2*2*B_*H_*2);
  f16* hx1    = (f16*)alloc((size_t)2*B_*H_*2);
  float* cstate=(float*)alloc((size_t)B_*H_*4);
  float* h1f  = (float*)alloc((size_t)B_*H_*4);
  float* Mf   = (float*)alloc(2*512*4);
  float* bf   = (float*)alloc(256);
  u32* flagsA = (u32*)alloc((size_t)FA_WORDS_*4);    // 256 KB padded flags
  u32* flagsC = (u32*)alloc((size_t)FC_WORDS_*4);    // 128 KB
  // fixed ~82 MB; Z1c chunk adaptive
  size_t used = (size_t)(p - (char*)d_ws);
  int CH = 8;
  for (int c = 256; c >= 8; c >>= 1){
    if (used + (size_t)c*B_*G_*2 <= ws_size){ CH = c; break; }
  }
  f16* Z1c = (f16*)alloc((size_t)CH*B_*G_*2);
  const int NC = S_/CH;

  int n;
  n = G_*EP_; k_pad_w<<<(n+255)/256, 256, 0, stream>>>(wih0f, w0fp, G_, E_, EP_);
              k_pad_w<<<(n+255)/256, 256, 0, stream>>>(wih0r, w0rp, G_, E_, EP_);
  n = G_*H_;  k_f32_to_f16<<<(n+255)/256,256,0,stream>>>(whh0f, whf, n);
              k_f32_to_f16<<<(n+255)/256,256,0,stream>>>(whh0r, whr, n);
              k_f32_to_f16<<<(n+255)/256,256,0,stream>>>(whh1r, w1h, n);
  n = G_*D1_; k_f32_to_f16<<<(n+255)/256,256,0,stream>>>(wih1r, w1i, n);
  k_bias<<<8,256,0,stream>>>(bih0f, bhh0f, bs0, G_);
  k_bias<<<8,256,0,stream>>>(bih0r, bhh0r, bs0 + G_, G_);
  k_bias<<<8,256,0,stream>>>(bih1r, bhh1r, bs1r, G_);
  k_len<<<1,128,0,stream>>>(x, len);
  k_init<<<(B_*H_+255)/256,256,0,stream>>>(hxA, hx1, cstate);
  k_zero<<<(FA_WORDS_+255)/256,256,0,stream>>>(flagsA, FA_WORDS_);
  k_zero<<<(FC_WORDS_+255)/256,256,0,stream>>>(flagsC, FC_WORDS_);
  k_fold<<<4,256,0,stream>>>(fc1w, fc1b, fcw, fcb, Mf, bf);

  // ---- phase A: layer-0 fwd+rev, single persistent launch ----
  k_phaseA<<<dim3(2,32,2), 256, 0, stream>>>(
      x, w0fp, w0rp, whf, whr, bs0, len, hxA, outcat, flagsA);

  // ---- phase C: per chunk, dense Z1 GEMM then recurrence ----
  for (int cc = 0; cc < NC; ++cc){
    int t0 = S_ - (cc+1)*CH;     // chunk covers t in [t0, t0+CH), consumed descending
    k_gemm_bt<<<dim3(CH*2,32), 256, 0, stream>>>(
        outcat + (size_t)t0*B_*D1_, w1i, Z1c, bs1r, CH*B_, G_, D1_);
    k_phaseCrec<<<dim3(2,32), 256, 0, stream>>>(
        Z1c, w1h, len, hx1, cstate, h1f, flagsC, cc*CH, CH);
  }

  k_final<<<1,256,0,stream>>>(h1f, Mf, bf, out);
}

// Round 11
// 3977.802 us; speedup vs baseline: 1.1768x; 1.1768x over previous
//
#include <hip/hip_runtime.h>

#define B_  128
#define S_  256
#define E_  300
#define EP_ 320
#define H_  512
#define G_  2048   // 4*H
#define D1_ 1024   // 2*H
// padded flags: [grp][slot(4)][wave(4)][jb(32)] x 32 u32 (128B line each)
#define FSLOT_ 4
#define FA_WORDS_ (4*FSLOT_*4*32*32)
#define FC_WORDS_ (2*FSLOT_*4*32*32)

typedef _Float16 f16;
typedef __attribute__((ext_vector_type(8))) _Float16 f16x8;
typedef __attribute__((ext_vector_type(4))) float    f32x4;
typedef unsigned long long u64;
typedef unsigned int u32;

__device__ __forceinline__ float sigf(float x){ return 1.f/(1.f + __expf(-x)); }
__device__ __forceinline__ float tanhf_(float x){
  float e = __expf(-2.f*fabsf(x));
  float t = (1.f - e)/(1.f + e);
  return x < 0.f ? -t : t;
}

// Relaxed agent-scope atomics route to the coherence point, bypassing the
// non-coherent per-XCD L2s.
// Ledger (us/step, phaseA): R1 fetch_add 11.0; R2 same-line flags 12.2; R4
// tagged 14.2; R5 batch h-loads 10.35; R7 Wi->LDS + x-reg-prefetch 8.8;
// R8 line-padded write-once flags 8.0 (BEST, total 4108); R9 prefetch-after-
// h-loads 9.2 (REGRESSED -> prefetch belongs in the poll's dead time, not
// competing with critical h-loads). R11: phaseA/phaseCrec reverted to R8;
// k_gemm_bt upgraded 64^2-naive -> 128^2 + global_load_lds (m97 recipe).
__device__ __forceinline__ u64 aload64(const u64* p){
  return __hip_atomic_load((u64*)p, __ATOMIC_RELAXED, __HIP_MEMORY_SCOPE_AGENT);
}
__device__ __forceinline__ u32 aload32(const u32* p){
  return __hip_atomic_load((u32*)p, __ATOMIC_RELAXED, __HIP_MEMORY_SCOPE_AGENT);
}
__device__ __forceinline__ void astore32(u32* p, u32 v){
  __hip_atomic_store(p, v, __ATOMIC_RELAXED, __HIP_MEMORY_SCOPE_AGENT);
}
union H8 { u64 q[2]; f16x8 v; };
union FU { f16 f; unsigned short s; };

// ---------------- setup kernels ----------------

__global__ void k_f32_to_f16(const float* __restrict__ s, f16* __restrict__ d, int n){
  int i = blockIdx.x*blockDim.x + threadIdx.x;
  if (i < n) d[i] = (f16)s[i];
}

__global__ void k_pad_w(const float* __restrict__ s, f16* __restrict__ d, int rows, int ks, int kd){
  int i = blockIdx.x*blockDim.x + threadIdx.x;
  if (i >= rows*kd) return;
  int r = i/kd, k = i - r*kd;
  d[i] = (k < ks) ? (f16)s[(size_t)r*ks + k] : (f16)0.f;
}

__global__ void k_bias(const float* __restrict__ a, const float* __restrict__ b,
                       float* __restrict__ d, int n){
  int i = blockIdx.x*blockDim.x + threadIdx.x;
  if (i < n) d[i] = a[i] + b[i];
}

__global__ void k_len(const float* __restrict__ x, int* __restrict__ len){
  int b = threadIdx.x;
  if (b < B_){
    int v = (int)x[((size_t)b*S_ + (S_-1))*E_];
    len[b] = v > S_ ? S_ : v;
  }
}

__global__ void k_zero(u32* __restrict__ p, int n){
  int i = blockIdx.x*blockDim.x + threadIdx.x;
  if (i < n) p[i] = 0u;
}

// hxA: [dir][parity][B*H], hx1: [parity][B*H]; parity-0 = h0 = 1. cstate = c0 = 1.
__global__ void k_init(f16* hxA, f16* hx1, float* cstate){
  int i = blockIdx.x*blockDim.x + threadIdx.x;
  if (i < B_*H_){
    hxA[i] = (f16)1.f;                // dir0 par0
    hxA[2*B_*H_ + i] = (f16)1.f;      // dir1 par0
    hx1[i] = (f16)1.f;                // par0
    cstate[i] = 1.f;
  }
}

// ---------------- GEMM: C[M,N] = A[M,K] @ B[N,K]^T + bias (f16 in/out, fp32 acc) ----
// R11: 128x128 tile, BK=32, 256 thr (4 waves, 2x2 quadrants of 64x64, 4x4
// MFMA accs each). Staging via global_load_lds width=16 into LINEAR row-major
// LDS [row][32] (m97 recipe: gload_lds needs linear dest; accept ds_read bank
// conflicts). M multiple of 128 (M=CH*128), N=2048, K=1024 -> no guards.

__global__ __launch_bounds__(256) void k_gemm_bt(
    const f16* __restrict__ A, const f16* __restrict__ Bm,
    f16* __restrict__ C, const float* __restrict__ bias,
    int M, int N, int K)
{
  __shared__ f16 As[128*32];   // 8 KB
  __shared__ f16 Bs[128*32];   // 8 KB
  const int m0 = blockIdx.x*128, n0 = blockIdx.y*128;
  const int tid = threadIdx.x;
  const int w = tid>>6, lane = tid&63, quad = lane>>4, l16 = lane&15;
  const int wm = (w&1)*64, wn = (w>>1)*64;   // wave's 64x64 quadrant
  // staging: wave w covers rows [w*32, w*32+32) as 2 segments of 16 rows;
  // lane l -> (row = seg*16 + l/4, 8 f16 at col (l%4)*8); LDS dest linear.
  const int srow = w*32 + (lane>>2);
  const int scol = (lane&3)*8;
  const f16* Ap  = A  + (size_t)(m0 + srow)*K + scol;
  const f16* Bp  = Bm + (size_t)(n0 + srow)*K + scol;
  const f16* Ap2 = Ap + (size_t)16*K;
  const f16* Bp2 = Bp + (size_t)16*K;
  f16* ldsA  = &As[(w*32)*32];       // wave-uniform bases
  f16* ldsA2 = &As[(w*32+16)*32];
  f16* ldsB  = &Bs[(w*32)*32];
  f16* ldsB2 = &Bs[(w*32+16)*32];
  f32x4 z4 = {0.f,0.f,0.f,0.f};
  f32x4 acc[4][4];
#pragma unroll
  for (int mi = 0; mi < 4; ++mi)
#pragma unroll
    for (int ni = 0; ni < 4; ++ni) acc[mi][ni] = z4;

  for (int k0 = 0; k0 < K; k0 += 32){
    __builtin_amdgcn_global_load_lds(
        (const __attribute__((address_space(1))) void*)(Ap + k0),
        (__attribute__((address_space(3))) void*)ldsA, 16, 0, 0);
    __builtin_amdgcn_global_load_lds(
        (const __attribute__((address_space(1))) void*)(Ap2 + k0),
        (__attribute__((address_space(3))) void*)ldsA2, 16, 0, 0);
    __builtin_amdgcn_global_load_lds(
        (const __attribute__((address_space(1))) void*)(Bp + k0),
        (__attribute__((address_space(3))) void*)ldsB, 16, 0, 0);
    __builtin_amdgcn_global_load_lds(
        (const __attribute__((address_space(1))) void*)(Bp2 + k0),
        (__attribute__((address_space(3))) void*)ldsB2, 16, 0, 0);
    asm volatile("s_waitcnt vmcnt(0)" ::: "memory");
    __syncthreads();
    f16x8 a[4], b[4];
#pragma unroll
    for (int mi = 0; mi < 4; ++mi)
      a[mi] = *(const f16x8*)&As[(wm + mi*16 + l16)*32 + quad*8];
#pragma unroll
    for (int ni = 0; ni < 4; ++ni)
      b[ni] = *(const f16x8*)&Bs[(wn + ni*16 + l16)*32 + quad*8];
#pragma unroll
    for (int mi = 0; mi < 4; ++mi)
#pragma unroll
      for (int ni = 0; ni < 4; ++ni)
        acc[mi][ni] = __builtin_amdgcn_mfma_f32_16x16x32_f16(a[mi], b[ni], acc[mi][ni],0,0,0);
    __syncthreads();
  }
#pragma unroll
  for (int mi = 0; mi < 4; ++mi)
#pragma unroll
    for (int ni = 0; ni < 4; ++ni){
      int col = n0 + wn + ni*16 + l16;
      float bz = bias[col];
#pragma unroll
      for (int r = 0; r < 4; ++r){
        int row = m0 + wm + mi*16 + quad*4 + r;
        C[(size_t)row*N + col] = (f16)(acc[mi][ni][r] + bz);
      }
    }
}

// ---------------- phase A: persistent layer-0 fwd+rev, column-partitioned ----------------
// grid (2,32,2) = 128 blocks, 256 thr. Block: 64 batch rows x 16 hidden x 4 gates.
// LDS: W_hh 64KB + W_ih 40KB (staged once, XOR-swizzled). x_t prefetched one
// step ahead into raw f32 regs during the poll's dead time (R8 placement —
// R9's after-h-loads placement regressed). Sync: per-(wave,jb) write-once
// flag on its own 128B line, value s+1, 4-slot window; producer vmcnt(0)+
// flag; consumer 32-lane gather + ballot. No syncthreads, no RMW.

__global__ __launch_bounds__(256, 1) void k_phaseA(
    const float* __restrict__ x,
    const f16* __restrict__ w0f, const f16* __restrict__ w0r,
    const f16* __restrict__ whf, const f16* __restrict__ whr,
    const float* __restrict__ bs0, const int* __restrict__ len,
    f16* __restrict__ hxA, f16* __restrict__ outcat,
    u32* __restrict__ flagsA)
{
  __shared__ f16 Wh[64*512];   // 64 KB
  __shared__ f16 Wi[64*320];   // 40 KB
  const int half = blockIdx.x, jb = blockIdx.y, dir = blockIdx.z;
  const f16* wih = dir ? w0r : w0f;
  const f16* whh = dir ? whr : whf;
  const float* bias = bs0 + dir*G_;
  f16* hx = hxA + (size_t)dir*(2*B_*H_);
  u32* fbase = flagsA + (size_t)(dir*2 + half)*(FSLOT_*4*32*32);
  const int tid = threadIdx.x;
  const int w = tid>>6, lane = tid&63, quad = lane>>4, l16 = lane&15;
  const int j0 = jb*16;
  const int m0 = half*64 + w*16;       // this wave's 16 batch rows

  for (int u = tid; u < 4096; u += 256){
    int lrr = u>>6, uc = u&63;
    int g = lrr>>4, i = lrr&15;
    *(uint4*)&Wh[lrr*512 + (uc ^ (i&7))*8] =
        *(const uint4*)(whh + ((size_t)(g*H_ + j0 + i))*H_ + uc*8);
  }
  // W_ih slice: 64 rows x 40 chunks of 8 f16; chunk XOR-swizzled per row
  for (int u = tid; u < 2560; u += 256){
    int row = u/40, c = u - row*40;
    int g = row>>4, i = row&15;
    *(uint4*)&Wi[row*320 + (c ^ (i&7))*8] =
        *(const uint4*)(wih + ((size_t)(g*H_ + j0 + i))*EP_ + c*8);
  }
  __syncthreads();

  const int j = j0 + l16;
  float bz[4], hprev[4], cpr[4]; int lm[4];
#pragma unroll
  for (int g = 0; g < 4; ++g) bz[g] = bias[g*H_ + j];
#pragma unroll
  for (int r = 0; r < 4; ++r){ hprev[r] = 1.f; cpr[r] = 1.f; lm[r] = len[m0 + quad*4 + r]; }
  const size_t xrowbase = (size_t)(m0 + l16)*S_;

  // --- cross-step x prefetch state (raw f32; cvt deferred to consumption) ---
  float4 xA[9], xB[9]; float xT[8];
  {
    const int t0 = dir ? (S_-1) : 0;
    const float* xr = x + (xrowbase + t0)*E_;
#pragma unroll
    for (int kb = 0; kb < 9; ++kb){
      xA[kb] = *(const float4*)(xr + kb*32 + quad*8);
      xB[kb] = *(const float4*)(xr + kb*32 + quad*8 + 4);
    }
    int kbase = 288 + quad*8;
#pragma unroll
    for (int e2 = 0; e2 < 8; ++e2)
      xT[e2] = (kbase + e2 < E_) ? xr[kbase + e2] : 0.f;
  }

  for (int s = 0; s < S_; ++s){
    const int t = dir ? (S_-1-s) : s;
    f32x4 z4 = {0.f,0.f,0.f,0.f};
    f32x4 acc[4] = {z4,z4,z4,z4};

    // --- x_t @ Wih^T from prefetched regs + LDS weights ---
#pragma unroll
    for (int kb = 0; kb < 9; ++kb){
      f16x8 a;
      a[0]=(f16)xA[kb].x; a[1]=(f16)xA[kb].y; a[2]=(f16)xA[kb].z; a[3]=(f16)xA[kb].w;
      a[4]=(f16)xB[kb].x; a[5]=(f16)xB[kb].y; a[6]=(f16)xB[kb].z; a[7]=(f16)xB[kb].w;
      int c = (kb*4 + quad) ^ (l16 & 7);
#pragma unroll
      for (int g = 0; g < 4; ++g){
        f16x8 b = *(const f16x8*)&Wi[(g*16+l16)*320 + c*8];
        acc[g] = __builtin_amdgcn_mfma_f32_16x16x32_f16(a, b, acc[g],0,0,0);
      }
    }
    { // K tail 288..319 (x zero-padded in regs; weight pad cols are zero)
      f16x8 a;
#pragma unroll
      for (int e2 = 0; e2 < 8; ++e2) a[e2] = (f16)xT[e2];
      int c = (36 + quad) ^ (l16 & 7);
#pragma unroll
      for (int g = 0; g < 4; ++g){
        f16x8 b = *(const f16x8*)&Wi[(g*16+l16)*320 + c*8];
        acc[g] = __builtin_amdgcn_mfma_f32_16x16x32_f16(a, b, acc[g],0,0,0);
      }
    }

    // --- issue next-step x prefetch (overlaps poll + h-GEMM + publish) ---
    if (s+1 < S_){
      const int tn = dir ? (S_-2-s) : (s+1);
      const float* xr = x + (xrowbase + tn)*E_;
#pragma unroll
      for (int kb = 0; kb < 9; ++kb){
        xA[kb] = *(const float4*)(xr + kb*32 + quad*8);
        xB[kb] = *(const float4*)(xr + kb*32 + quad*8 + 4);
      }
      int kbase = 288 + quad*8;
#pragma unroll
      for (int e2 = 0; e2 < 8; ++e2)
        xT[e2] = (kbase + e2 < E_) ? xr[kbase + e2] : 0.f;
    }

    // --- poll: 32 padded flags (32 distinct lines), one gather + ballot ---
    if (s > 0){
      const u32* fp = fbase + ((size_t)((s-1)&(FSLOT_-1))*4 + w)*32*32;
      const u32 expv = (u32)s;
      for (;;){
        u32 v = aload32(fp + (size_t)(lane & 31)*32);
        if (__ballot(v == expv) == ~0ull) break;
      }
      asm volatile("" ::: "memory");   // keep h loads below the poll
    }

    // --- h @ Whh^T (K=512): batch-issue ALL 32 coherence-point loads, then MFMA ---
    const int par = s & 1;
    const u64* hap = (const u64*)(hx + (size_t)par*(B_*H_) + (size_t)(m0 + l16)*H_);
    u64 hq[32];
#pragma unroll
    for (int kb = 0; kb < 16; ++kb){
      hq[2*kb]   = aload64(hap + kb*8 + quad*2);
      hq[2*kb+1] = aload64(hap + kb*8 + quad*2 + 1);
    }
#pragma unroll
    for (int kb = 0; kb < 16; ++kb){
      H8 ha;
      ha.q[0] = hq[2*kb];
      ha.q[1] = hq[2*kb+1];
      int uq = kb*4 + quad;
#pragma unroll
      for (int g = 0; g < 4; ++g){
        f16x8 b = *(const f16x8*)&Wh[(g*16+l16)*512 + ((uq ^ (l16&7)))*8];
        acc[g] = __builtin_amdgcn_mfma_f32_16x16x32_f16(ha.v, b, acc[g],0,0,0);
      }
    }

    // --- gates + state update; publish h (packed 4B, even lanes) ---
    f16* hn = hx + (size_t)(1-par)*(B_*H_);
#pragma unroll
    for (int r = 0; r < 4; ++r){
      int m = m0 + quad*4 + r;
      float zi = acc[0][r] + bz[0];
      float zf = acc[1][r] + bz[1];
      float zg = acc[2][r] + bz[2];
      float zo = acc[3][r] + bz[3];
      float ig = sigf(zi), fg = sigf(zf), gg = tanhf_(zg), og = sigf(zo);
      float cnew = fg*cpr[r] + ig*gg;
      float hnew = og*tanhf_(cnew);
      bool mk = t < lm[r];
      float hsel = mk ? hnew : hprev[r];
      cpr[r] = mk ? cnew : cpr[r];
      hprev[r] = hsel;
      FU cv; cv.f = (f16)hsel;
      int other = __shfl_down((int)cv.s, 1);
      if ((l16 & 1) == 0)
        astore32((u32*)(hn + (size_t)m*H_ + j), (u32)cv.s | ((u32)other << 16));
    }
    // per-wave drain (covers h stores, old-parity reads, and the prefetch),
    // then write-once flag on this (wave,jb)'s private 128B line
    asm volatile("s_waitcnt vmcnt(0)" ::: "memory");
    if (lane == 0)
      astore32(fbase + (((size_t)(s&(FSLOT_-1))*4 + w)*32 + jb)*32, (u32)(s+1));

    // --- deferred outcat stores (off the inter-block critical path) ---
#pragma unroll
    for (int r = 0; r < 4; ++r){
      int m = m0 + quad*4 + r;
      FU cv; cv.f = (f16)hprev[r];
      int other = __shfl_down((int)cv.s, 1);
      if ((l16 & 1) == 0)
        *(u32*)(outcat + ((size_t)t*B_ + m)*D1_ + dir*H_ + j) = (u32)cv.s | ((u32)other << 16);
    }
  }
}

// ---------------- phase C recurrence: layer-1 reverse over one CH-step chunk ----------------
// grid (2,32) = 64 blocks. R8 structure: Z prefetch before the poll (dead-time
// placement), padded flags, batch h-loads.

__global__ __launch_bounds__(256, 1) void k_phaseCrec(
    const f16* __restrict__ Z1c, const f16* __restrict__ w1h,
    const int* __restrict__ len,
    f16* __restrict__ hx1, float* __restrict__ cstate, float* __restrict__ h1f,
    u32* __restrict__ flagsC, int s0, int CH)
{
  __shared__ f16 Wh[64*512];   // 64 KB
  const int half = blockIdx.x, jb = blockIdx.y;
  u32* fbase = flagsC + (size_t)half*(FSLOT_*4*32*32);
  const int tid = threadIdx.x;
  const int w = tid>>6, lane = tid&63, quad = lane>>4, l16 = lane&15;
  const int j0 = jb*16;
  const int m0 = half*64 + w*16;

  for (int u = tid; u < 4096; u += 256){
    int lrr = u>>6, uc = u&63;
    int g = lrr>>4, i = lrr&15;
    *(uint4*)&Wh[lrr*512 + (uc ^ (i&7))*8] =
        *(const uint4*)(w1h + ((size_t)(g*H_ + j0 + i))*H_ + uc*8);
  }
  __syncthreads();

  const int j = j0 + l16;
  float hprev[4], cpr[4]; int lm[4];
#pragma unroll
  for (int r = 0; r < 4; ++r){
    int m = m0 + quad*4 + r;
    lm[r] = len[m];
    cpr[r] = cstate[(size_t)m*H_ + j];
    hprev[r] = (float)hx1[(size_t)(s0 & 1)*(B_*H_) + (size_t)m*H_ + j];
  }

  for (int sl = 0; sl < CH; ++sl){
    const int s = s0 + sl;
    const int t = S_-1-s;
    const int zrow = CH-1-sl;

    // --- prefetch Z rows (h-independent; overlaps the wait) ---
    float zv[4][4];
#pragma unroll
    for (int g = 0; g < 4; ++g)
#pragma unroll
      for (int r = 0; r < 4; ++r)
        zv[g][r] = (float)Z1c[((size_t)zrow*B_ + m0 + quad*4 + r)*G_ + g*H_ + j];

    if (s > 0){
      const u32* fp = fbase + ((size_t)((s-1)&(FSLOT_-1))*4 + w)*32*32;
      const u32 expv = (u32)s;
      for (;;){
        u32 v = aload32(fp + (size_t)(lane & 31)*32);
        if (__ballot(v == expv) == ~0ull) break;
      }
      asm volatile("" ::: "memory");
    }

    // --- h @ Whh1^T (K=512): batch-issue loads, then MFMA ---
    const int par = s & 1;
    const u64* hap = (const u64*)(hx1 + (size_t)par*(B_*H_) + (size_t)(m0 + l16)*H_);
    f32x4 z4 = {0.f,0.f,0.f,0.f};
    f32x4 acc[4] = {z4,z4,z4,z4};
    u64 hq[32];
#pragma unroll
    for (int kb = 0; kb < 16; ++kb){
      hq[2*kb]   = aload64(hap + kb*8 + quad*2);
      hq[2*kb+1] = aload64(hap + kb*8 + quad*2 + 1);
    }
#pragma unroll
    for (int kb = 0; kb < 16; ++kb){
      H8 ha;
      ha.q[0] = hq[2*kb];
      ha.q[1] = hq[2*kb+1];
      int uq = kb*4 + quad;
#pragma unroll
      for (int g = 0; g < 4; ++g){
        f16x8 b = *(const f16x8*)&Wh[(g*16+l16)*512 + ((uq ^ (l16&7)))*8];
        acc[g] = __builtin_amdgcn_mfma_f32_16x16x32_f16(ha.v, b, acc[g],0,0,0);
      }
    }

    f16* hn = hx1 + (size_t)(1-par)*(B_*H_);
#pragma unroll
    for (int r = 0; r < 4; ++r){
      int m = m0 + quad*4 + r;
      float zi = acc[0][r] + zv[0][r];
      float zf = acc[1][r] + zv[1][r];
      float zg = acc[2][r] + zv[2][r];
      float zo = acc[3][r] + zv[3][r];
      float ig = sigf(zi), fg = sigf(zf), gg = tanhf_(zg), og = sigf(zo);
      float cnew = fg*cpr[r] + ig*gg;
      float hnew = og*tanhf_(cnew);
      bool mk = t < lm[r];
      float hsel = mk ? hnew : hprev[r];
      cpr[r] = mk ? cnew : cpr[r];
      hprev[r] = hsel;
      FU cv; cv.f = (f16)hsel;
      int other = __shfl_down((int)cv.s, 1);
      if ((l16 & 1) == 0)
        astore32((u32*)(hn + (size_t)m*H_ + j), (u32)cv.s | ((u32)other << 16));
    }
    asm volatile("s_waitcnt vmcnt(0)" ::: "memory");
    if (lane == 0)
      astore32(fbase + (((size_t)(s&(FSLOT_-1))*4 + w)*32 + jb)*32, (u32)(s+1));

    if (t == 0){  // deferred final-state write (consumed by k_final after kernel end)
#pragma unroll
      for (int r = 0; r < 4; ++r)
        h1f[(size_t)(m0 + quad*4 + r)*H_ + j] = hprev[r];
    }
  }

  // persist c across chunk launches (h lives in hx1 parity buffers)
#pragma unroll
  for (int r = 0; r < 4; ++r)
    cstate[(size_t)(m0 + quad*4 + r)*H_ + j] = cpr[r];
}

// ---------------- epilogue: folded FC ----------------

__global__ void k_fold(const float* __restrict__ fc1w, const float* __restrict__ fc1b,
                       const float* __restrict__ fcw,  const float* __restrict__ fcb,
                       float* __restrict__ Mf, float* __restrict__ bf){
  int i = blockIdx.x*blockDim.x + threadIdx.x;
  if (i >= 1024) return;
  int o = i >> 9, h = i & 511;
  float s = 0.f;
  for (int jj = 0; jj < 512; ++jj) s += fcw[o*512 + jj] * fc1w[jj*512 + h];
  Mf[o*512 + h] = s;
  if (h == 0){
    float sb = fcb[o];
    for (int jj = 0; jj < 512; ++jj) sb += fcw[o*512 + jj] * fc1b[jj];
    bf[o] = sb;
  }
}

__global__ void k_final(const float* __restrict__ h1f, const float* __restrict__ Mf,
                        const float* __restrict__ bf, float* __restrict__ out){
  int i = threadIdx.x;
  if (i >= 256) return;
  int b = i >> 1, o = i & 1;
  float s = bf[o];
  const float* hp = h1f + (size_t)b*512;
  const float* mp = Mf + (size_t)o*512;
  for (int h = 0; h < 512; ++h) s += hp[h]*mp[h];
  out[b*2 + o] = s;
}

// ---------------- host ----------------

extern "C" void kernel_launch(void* const* d_in, const int* in_sizes, int n_in,
                              void* d_out, int out_size, void* d_ws, size_t ws_size,
                              hipStream_t stream)
{
  const float* x     = (const float*)d_in[0];
  const float* wih0f = (const float*)d_in[1];
  const float* whh0f = (const float*)d_in[2];
  const float* bih0f = (const float*)d_in[3];
  const float* bhh0f = (const float*)d_in[4];
  const float* wih0r = (const float*)d_in[5];
  const float* whh0r = (const float*)d_in[6];
  const float* bih0r = (const float*)d_in[7];
  const float* bhh0r = (const float*)d_in[8];
  // d_in[9..12] = layer1 forward: dead code (only hT_r of layer1 reaches output)
  const float* wih1r = (const float*)d_in[13];
  const float* whh1r = (const float*)d_in[14];
  const float* bih1r = (const float*)d_in[15];
  const float* bhh1r = (const float*)d_in[16];
  const float* fc1w  = (const float*)d_in[17];
  const float* fc1b  = (const float*)d_in[18];
  const float* fcw   = (const float*)d_in[19];
  const float* fcb   = (const float*)d_in[20];
  float* out = (float*)d_out;

  char* p = (char*)d_ws;
  auto alloc = [&](size_t bytes)->char*{
    char* r = p; p += (bytes + 255) & ~(size_t)255; return r;
  };
  f16* w0fp   = (f16*)alloc((size_t)G_*EP_*2);       // 1.3 MB
  f16* w0rp   = (f16*)alloc((size_t)G_*EP_*2);
  f16* whf    = (f16*)alloc((size_t)G_*H_*2);        // 2 MB
  f16* whr    = (f16*)alloc((size_t)G_*H_*2);
  f16* w1i    = (f16*)alloc((size_t)G_*D1_*2);       // 4 MB
  f16* w1h    = (f16*)alloc((size_t)G_*H_*2);        // 2 MB
  float* bs0  = (float*)alloc((size_t)2*G_*4);
  float* bs1r = (float*)alloc(G_*4);
  int*   len  = (int*)alloc(B_*4);
  f16* outcat = (f16*)alloc((size_t)S_*B_*D1_*2);    // 67 MB
  f16* hxA    = (f16*)alloc((size_t)2*2*B_*H_*2);
  f16* hx1    = (f16*)alloc((size_t)2*B_*H_*2);
  float* cstate=(float*)alloc((size_t)B_*H_*4);
  float* h1f  = (float*)alloc((size_t)B_*H_*4);
  float* Mf   = (float*)alloc(2*512*4);
  float* bf   = (float*)alloc(256);
  u32* flagsA = (u32*)alloc((size_t)FA_WORDS_*4);    // 256 KB padded flags
  u32* flagsC = (u32*)alloc((size_t)FC_WORDS_*4);    // 128 KB
  // fixed ~82 MB; Z1c chunk adaptive
  size_t used = (size_t)(p - (char*)d_ws);
  int CH = 8;
  for (int c = 256; c >= 8; c >>= 1){
    if (used + (size_t)c*B_*G_*2 <= ws_size){ CH = c; break; }
  }
  f16* Z1c = (f16*)alloc((size_t)CH*B_*G_*2);
  const int NC = S_/CH;

  int n;
  n = G_*EP_; k_pad_w<<<(n+255)/256, 256, 0, stream>>>(wih0f, w0fp, G_, E_, EP_);
              k_pad_w<<<(n+255)/256, 256, 0, stream>>>(wih0r, w0rp, G_, E_, EP_);
  n = G_*H_;  k_f32_to_f16<<<(n+255)/256,256,0,stream>>>(whh0f, whf, n);
              k_f32_to_f16<<<(n+255)/256,256,0,stream>>>(whh0r, whr, n);
              k_f32_to_f16<<<(n+255)/256,256,0,stream>>>(whh1r, w1h, n);
  n = G_*D1_; k_f32_to_f16<<<(n+255)/256,256,0,stream>>>(wih1r, w1i, n);
  k_bias<<<8,256,0,stream>>>(bih0f, bhh0f, bs0, G_);
  k_bias<<<8,256,0,stream>>>(bih0r, bhh0r, bs0 + G_, G_);
  k_bias<<<8,256,0,stream>>>(bih1r, bhh1r, bs1r, G_);
  k_len<<<1,128,0,stream>>>(x, len);
  k_init<<<(B_*H_+255)/256,256,0,stream>>>(hxA, hx1, cstate);
  k_zero<<<(FA_WORDS_+255)/256,256,0,stream>>>(flagsA, FA_WORDS_);
  k_zero<<<(FC_WORDS_+255)/256,256,0,stream>>>(flagsC, FC_WORDS_);
  k_fold<<<4,256,0,stream>>>(fc1w, fc1b, fcw, fcb, Mf, bf);

  // ---- phase A: layer-0 fwd+rev, single persistent launch ----
  k_phaseA<<<dim3(2,32,2), 256, 0, stream>>>(
      x, w0fp, w0rp, whf, whr, bs0, len, hxA, outcat, flagsA);

  // ---- phase C: per chunk, dense Z1 GEMM (128^2 tile) then recurrence ----
  for (int cc = 0; cc < NC; ++cc){
    int t0 = S_ - (cc+1)*CH;     // chunk covers t in [t0, t0+CH), consumed descending
    k_gemm_bt<<<dim3(CH, 16), 256, 0, stream>>>(
        outcat + (size_t)t0*B_*D1_, w1i, Z1c, bs1r, CH*B_, G_, D1_);
    k_phaseCrec<<<dim3(2,32), 256, 0, stream>>>(
        Z1c, w1h, len, hx1, cstate, h1f, flagsC, cc*CH, CH);
  }

  k_final<<<1,256,0,stream>>>(h1f, Mf, bf, out);
}

// Round 12
// 3970.972 us; speedup vs baseline: 1.1788x; 1.0017x over previous
//
#include <hip/hip_runtime.h>

#define B_  128
#define S_  256
#define E_  300
#define EP_ 320
#define H_  512
#define G_  2048   // 4*H
#define D1_ 1024   // 2*H
#define G2_ 4096   // both dirs concat
// padded flags: [grp][slot(4)][wave(4)][jb(32)] x 32 u32 (128B line each)
#define FSLOT_ 4
#define FA_WORDS_ (4*FSLOT_*4*32*32)
#define FC_WORDS_ (2*FSLOT_*4*32*32)

typedef _Float16 f16;
typedef __attribute__((ext_vector_type(8))) _Float16 f16x8;
typedef __attribute__((ext_vector_type(4))) float    f32x4;
typedef unsigned long long u64;
typedef unsigned int u32;

__device__ __forceinline__ float sigf(float x){ return 1.f/(1.f + __expf(-x)); }
__device__ __forceinline__ float tanhf_(float x){
  float e = __expf(-2.f*fabsf(x));
  float t = (1.f - e)/(1.f + e);
  return x < 0.f ? -t : t;
}

// Relaxed agent-scope atomics route to the coherence point, bypassing the
// non-coherent per-XCD L2s.
// Ledger (us/step, phaseA): R1 fetch_add 11.0; R2 same-line flags 12.2; R4
// tagged 14.2; R5 batch h-loads 10.35; R7 Wi->LDS + x-reg-prefetch 8.8;
// R8 line-padded write-once flags 8.0; R9 prefetch-after-h-loads 9.2
// (REGRESSED); R11 128^2 gemm 3978 total (phaseA 8.0, phaseC step ~5.7).
// R12: the 2.3us/step gap A-vs-C is the in-step x-GEMM sitting ON the serial
// chain. Precompute Xz = x @ [Wih_f||Wih_r]^T + bias as a dense GEMM before
// phaseA (the Z1c trick); phaseA steps become phaseC-shaped (16 f16 loads in
// poll dead time). Xz (268MB) aliases Z1c; ws-capacity fallback = exact R11.
__device__ __forceinline__ u64 aload64(const u64* p){
  return __hip_atomic_load((u64*)p, __ATOMIC_RELAXED, __HIP_MEMORY_SCOPE_AGENT);
}
__device__ __forceinline__ u32 aload32(const u32* p){
  return __hip_atomic_load((u32*)p, __ATOMIC_RELAXED, __HIP_MEMORY_SCOPE_AGENT);
}
__device__ __forceinline__ void astore32(u32* p, u32 v){
  __hip_atomic_store(p, v, __ATOMIC_RELAXED, __HIP_MEMORY_SCOPE_AGENT);
}
union H8 { u64 q[2]; f16x8 v; };
union FU { f16 f; unsigned short s; };

// ---------------- setup kernels ----------------

__global__ void k_f32_to_f16(const float* __restrict__ s, f16* __restrict__ d, int n){
  int i = blockIdx.x*blockDim.x + threadIdx.x;
  if (i < n) d[i] = (f16)s[i];
}

__global__ void k_pad_w(const float* __restrict__ s, f16* __restrict__ d, int rows, int ks, int kd){
  int i = blockIdx.x*blockDim.x + threadIdx.x;
  if (i >= rows*kd) return;
  int r = i/kd, k = i - r*kd;
  d[i] = (k < ks) ? (f16)s[(size_t)r*ks + k] : (f16)0.f;
}

// x[B,S,E] f32 -> xf[(t*B+m)*EP_] f16, zero-padded to EP_
__global__ void k_cast_x(const float* __restrict__ x, f16* __restrict__ xf){
  int i = blockIdx.x*blockDim.x + threadIdx.x;
  if (i >= S_*B_*EP_) return;
  int e = i % EP_; int rm = i / EP_;
  int m = rm % B_; int t = rm / B_;
  xf[i] = (e < E_) ? (f16)x[((size_t)m*S_ + t)*E_ + e] : (f16)0.f;
}

__global__ void k_bias(const float* __restrict__ a, const float* __restrict__ b,
                       float* __restrict__ d, int n){
  int i = blockIdx.x*blockDim.x + threadIdx.x;
  if (i < n) d[i] = a[i] + b[i];
}

__global__ void k_len(const float* __restrict__ x, int* __restrict__ len){
  int b = threadIdx.x;
  if (b < B_){
    int v = (int)x[((size_t)b*S_ + (S_-1))*E_];
    len[b] = v > S_ ? S_ : v;
  }
}

__global__ void k_zero(u32* __restrict__ p, int n){
  int i = blockIdx.x*blockDim.x + threadIdx.x;
  if (i < n) p[i] = 0u;
}

// hxA: [dir][parity][B*H], hx1: [parity][B*H]; parity-0 = h0 = 1. cstate = c0 = 1.
__global__ void k_init(f16* hxA, f16* hx1, float* cstate){
  int i = blockIdx.x*blockDim.x + threadIdx.x;
  if (i < B_*H_){
    hxA[i] = (f16)1.f;                // dir0 par0
    hxA[2*B_*H_ + i] = (f16)1.f;      // dir1 par0
    hx1[i] = (f16)1.f;                // par0
    cstate[i] = 1.f;
  }
}

// ---------------- GEMM: C[M,N] = A[M,K] @ B[N,K]^T + bias (f16 in/out, fp32 acc) ----
// 128x128 tile, BK=32, 256 thr (4 waves, 2x2 quadrants of 64x64, 4x4 MFMA accs
// each). Staging via global_load_lds width=16 into LINEAR row-major LDS
// [row][32]. M multiple of 128, N mult of 128, K mult of 32 -> no guards.

__global__ __launch_bounds__(256) void k_gemm_bt(
    const f16* __restrict__ A, const f16* __restrict__ Bm,
    f16* __restrict__ C, const float* __restrict__ bias,
    int M, int N, int K)
{
  __shared__ f16 As[128*32];   // 8 KB
  __shared__ f16 Bs[128*32];   // 8 KB
  const int m0 = blockIdx.x*128, n0 = blockIdx.y*128;
  const int tid = threadIdx.x;
  const int w = tid>>6, lane = tid&63, quad = lane>>4, l16 = lane&15;
  const int wm = (w&1)*64, wn = (w>>1)*64;   // wave's 64x64 quadrant
  const int srow = w*32 + (lane>>2);
  const int scol = (lane&3)*8;
  const f16* Ap  = A  + (size_t)(m0 + srow)*K + scol;
  const f16* Bp  = Bm + (size_t)(n0 + srow)*K + scol;
  const f16* Ap2 = Ap + (size_t)16*K;
  const f16* Bp2 = Bp + (size_t)16*K;
  f16* ldsA  = &As[(w*32)*32];       // wave-uniform bases
  f16* ldsA2 = &As[(w*32+16)*32];
  f16* ldsB  = &Bs[(w*32)*32];
  f16* ldsB2 = &Bs[(w*32+16)*32];
  f32x4 z4 = {0.f,0.f,0.f,0.f};
  f32x4 acc[4][4];
#pragma unroll
  for (int mi = 0; mi < 4; ++mi)
#pragma unroll
    for (int ni = 0; ni < 4; ++ni) acc[mi][ni] = z4;

  for (int k0 = 0; k0 < K; k0 += 32){
    __builtin_amdgcn_global_load_lds(
        (const __attribute__((address_space(1))) void*)(Ap + k0),
        (__attribute__((address_space(3))) void*)ldsA, 16, 0, 0);
    __builtin_amdgcn_global_load_lds(
        (const __attribute__((address_space(1))) void*)(Ap2 + k0),
        (__attribute__((address_space(3))) void*)ldsA2, 16, 0, 0);
    __builtin_amdgcn_global_load_lds(
        (const __attribute__((address_space(1))) void*)(Bp + k0),
        (__attribute__((address_space(3))) void*)ldsB, 16, 0, 0);
    __builtin_amdgcn_global_load_lds(
        (const __attribute__((address_space(1))) void*)(Bp2 + k0),
        (__attribute__((address_space(3))) void*)ldsB2, 16, 0, 0);
    asm volatile("s_waitcnt vmcnt(0)" ::: "memory");
    __syncthreads();
    f16x8 a[4], b[4];
#pragma unroll
    for (int mi = 0; mi < 4; ++mi)
      a[mi] = *(const f16x8*)&As[(wm + mi*16 + l16)*32 + quad*8];
#pragma unroll
    for (int ni = 0; ni < 4; ++ni)
      b[ni] = *(const f16x8*)&Bs[(wn + ni*16 + l16)*32 + quad*8];
#pragma unroll
    for (int mi = 0; mi < 4; ++mi)
#pragma unroll
      for (int ni = 0; ni < 4; ++ni)
        acc[mi][ni] = __builtin_amdgcn_mfma_f32_16x16x32_f16(a[mi], b[ni], acc[mi][ni],0,0,0);
    __syncthreads();
  }
#pragma unroll
  for (int mi = 0; mi < 4; ++mi)
#pragma unroll
    for (int ni = 0; ni < 4; ++ni){
      int col = n0 + wn + ni*16 + l16;
      float bz = bias[col];
#pragma unroll
      for (int r = 0; r < 4; ++r){
        int row = m0 + wm + mi*16 + quad*4 + r;
        C[(size_t)row*N + col] = (f16)(acc[mi][ni][r] + bz);
      }
    }
}

// ---------------- phase A: persistent layer-0 fwd+rev, column-partitioned ----------------
// grid (2,32,2) = 128 blocks, 256 thr. Block: 64 batch rows x 16 hidden x 4 gates.
// R12: if xz != null, the x-part is precomputed (Xz[(t*B+m)*G2_ + dir*G_ +
// g*H + j], bias folded) and each step only loads 16 f16 zv values in the
// poll's dead time -> step shaped like phaseC. Else: exact R11 path (Wi LDS +
// x reg-prefetch). Sync: per-(wave,jb) write-once flag on its own 128B line,
// value s+1, 4-slot window; producer vmcnt(0)+flag; consumer 32-lane gather
// + ballot. No syncthreads, no RMW.

__global__ __launch_bounds__(256, 1) void k_phaseA(
    const float* __restrict__ x, const f16* __restrict__ xz,
    const f16* __restrict__ w0f, const f16* __restrict__ w0r,
    const f16* __restrict__ whf, const f16* __restrict__ whr,
    const float* __restrict__ bs0, const int* __restrict__ len,
    f16* __restrict__ hxA, f16* __restrict__ outcat,
    u32* __restrict__ flagsA)
{
  __shared__ f16 Wh[64*512];   // 64 KB
  __shared__ f16 Wi[64*320];   // 40 KB
  const int half = blockIdx.x, jb = blockIdx.y, dir = blockIdx.z;
  const f16* wih = dir ? w0r : w0f;
  const f16* whh = dir ? whr : whf;
  const float* bias = bs0 + dir*G_;
  f16* hx = hxA + (size_t)dir*(2*B_*H_);
  u32* fbase = flagsA + (size_t)(dir*2 + half)*(FSLOT_*4*32*32);
  const int tid = threadIdx.x;
  const int w = tid>>6, lane = tid&63, quad = lane>>4, l16 = lane&15;
  const int j0 = jb*16;
  const int m0 = half*64 + w*16;       // this wave's 16 batch rows

  for (int u = tid; u < 4096; u += 256){
    int lrr = u>>6, uc = u&63;
    int g = lrr>>4, i = lrr&15;
    *(uint4*)&Wh[lrr*512 + (uc ^ (i&7))*8] =
        *(const uint4*)(whh + ((size_t)(g*H_ + j0 + i))*H_ + uc*8);
  }
  if (!xz){
    // W_ih slice: 64 rows x 40 chunks of 8 f16; chunk XOR-swizzled per row
    for (int u = tid; u < 2560; u += 256){
      int row = u/40, c = u - row*40;
      int g = row>>4, i = row&15;
      *(uint4*)&Wi[row*320 + (c ^ (i&7))*8] =
          *(const uint4*)(wih + ((size_t)(g*H_ + j0 + i))*EP_ + c*8);
    }
  }
  __syncthreads();

  const int j = j0 + l16;
  float bz[4], hprev[4], cpr[4]; int lm[4];
#pragma unroll
  for (int g = 0; g < 4; ++g) bz[g] = bias[g*H_ + j];
#pragma unroll
  for (int r = 0; r < 4; ++r){ hprev[r] = 1.f; cpr[r] = 1.f; lm[r] = len[m0 + quad*4 + r]; }
  const size_t xrowbase = (size_t)(m0 + l16)*S_;

  if (xz){
    // =========== Xz path: x-part precomputed, step shaped like phaseC ===========
    for (int s = 0; s < S_; ++s){
      const int t = dir ? (S_-1-s) : s;

      // --- zv loads (bias folded in GEMM); poll dead-time placement ---
      const f16* zr = xz + ((size_t)t*B_)*G2_ + dir*G_;
      float zvv[4][4];
#pragma unroll
      for (int g = 0; g < 4; ++g)
#pragma unroll
        for (int r = 0; r < 4; ++r)
          zvv[g][r] = (float)zr[(size_t)(m0 + quad*4 + r)*G2_ + g*H_ + j];

      if (s > 0){
        const u32* fp = fbase + ((size_t)((s-1)&(FSLOT_-1))*4 + w)*32*32;
        const u32 expv = (u32)s;
        for (;;){
          u32 v = aload32(fp + (size_t)(lane & 31)*32);
          if (__ballot(v == expv) == ~0ull) break;
        }
        asm volatile("" ::: "memory");
      }

      const int par = s & 1;
      const u64* hap = (const u64*)(hx + (size_t)par*(B_*H_) + (size_t)(m0 + l16)*H_);
      f32x4 z4 = {0.f,0.f,0.f,0.f};
      f32x4 acc[4] = {z4,z4,z4,z4};
      u64 hq[32];
#pragma unroll
      for (int kb = 0; kb < 16; ++kb){
        hq[2*kb]   = aload64(hap + kb*8 + quad*2);
        hq[2*kb+1] = aload64(hap + kb*8 + quad*2 + 1);
      }
#pragma unroll
      for (int kb = 0; kb < 16; ++kb){
        H8 ha;
        ha.q[0] = hq[2*kb];
        ha.q[1] = hq[2*kb+1];
        int uq = kb*4 + quad;
#pragma unroll
        for (int g = 0; g < 4; ++g){
          f16x8 b = *(const f16x8*)&Wh[(g*16+l16)*512 + ((uq ^ (l16&7)))*8];
          acc[g] = __builtin_amdgcn_mfma_f32_16x16x32_f16(ha.v, b, acc[g],0,0,0);
        }
      }

      f16* hn = hx + (size_t)(1-par)*(B_*H_);
#pragma unroll
      for (int r = 0; r < 4; ++r){
        int m = m0 + quad*4 + r;
        float zi = acc[0][r] + zvv[0][r];
        float zf = acc[1][r] + zvv[1][r];
        float zg = acc[2][r] + zvv[2][r];
        float zo = acc[3][r] + zvv[3][r];
        float ig = sigf(zi), fg = sigf(zf), gg = tanhf_(zg), og = sigf(zo);
        float cnew = fg*cpr[r] + ig*gg;
        float hnew = og*tanhf_(cnew);
        bool mk = t < lm[r];
        float hsel = mk ? hnew : hprev[r];
        cpr[r] = mk ? cnew : cpr[r];
        hprev[r] = hsel;
        FU cv; cv.f = (f16)hsel;
        int other = __shfl_down((int)cv.s, 1);
        if ((l16 & 1) == 0)
          astore32((u32*)(hn + (size_t)m*H_ + j), (u32)cv.s | ((u32)other << 16));
      }
      asm volatile("s_waitcnt vmcnt(0)" ::: "memory");
      if (lane == 0)
        astore32(fbase + (((size_t)(s&(FSLOT_-1))*4 + w)*32 + jb)*32, (u32)(s+1));

#pragma unroll
      for (int r = 0; r < 4; ++r){
        int m = m0 + quad*4 + r;
        FU cv; cv.f = (f16)hprev[r];
        int other = __shfl_down((int)cv.s, 1);
        if ((l16 & 1) == 0)
          *(u32*)(outcat + ((size_t)t*B_ + m)*D1_ + dir*H_ + j) = (u32)cv.s | ((u32)other << 16);
      }
    }
    return;
  }

  // =========== fallback: exact R11 path (in-kernel x-GEMM) ===========
  float4 xA[9], xB[9]; float xT[8];
  {
    const int t0 = dir ? (S_-1) : 0;
    const float* xr = x + (xrowbase + t0)*E_;
#pragma unroll
    for (int kb = 0; kb < 9; ++kb){
      xA[kb] = *(const float4*)(xr + kb*32 + quad*8);
      xB[kb] = *(const float4*)(xr + kb*32 + quad*8 + 4);
    }
    int kbase = 288 + quad*8;
#pragma unroll
    for (int e2 = 0; e2 < 8; ++e2)
      xT[e2] = (kbase + e2 < E_) ? xr[kbase + e2] : 0.f;
  }

  for (int s = 0; s < S_; ++s){
    const int t = dir ? (S_-1-s) : s;
    f32x4 z4 = {0.f,0.f,0.f,0.f};
    f32x4 acc[4] = {z4,z4,z4,z4};

#pragma unroll
    for (int kb = 0; kb < 9; ++kb){
      f16x8 a;
      a[0]=(f16)xA[kb].x; a[1]=(f16)xA[kb].y; a[2]=(f16)xA[kb].z; a[3]=(f16)xA[kb].w;
      a[4]=(f16)xB[kb].x; a[5]=(f16)xB[kb].y; a[6]=(f16)xB[kb].z; a[7]=(f16)xB[kb].w;
      int c = (kb*4 + quad) ^ (l16 & 7);
#pragma unroll
      for (int g = 0; g < 4; ++g){
        f16x8 b = *(const f16x8*)&Wi[(g*16+l16)*320 + c*8];
        acc[g] = __builtin_amdgcn_mfma_f32_16x16x32_f16(a, b, acc[g],0,0,0);
      }
    }
    {
      f16x8 a;
#pragma unroll
      for (int e2 = 0; e2 < 8; ++e2) a[e2] = (f16)xT[e2];
      int c = (36 + quad) ^ (l16 & 7);
#pragma unroll
      for (int g = 0; g < 4; ++g){
        f16x8 b = *(const f16x8*)&Wi[(g*16+l16)*320 + c*8];
        acc[g] = __builtin_amdgcn_mfma_f32_16x16x32_f16(a, b, acc[g],0,0,0);
      }
    }

    if (s+1 < S_){
      const int tn = dir ? (S_-2-s) : (s+1);
      const float* xr = x + (xrowbase + tn)*E_;
#pragma unroll
      for (int kb = 0; kb < 9; ++kb){
        xA[kb] = *(const float4*)(xr + kb*32 + quad*8);
        xB[kb] = *(const float4*)(xr + kb*32 + quad*8 + 4);
      }
      int kbase = 288 + quad*8;
#pragma unroll
      for (int e2 = 0; e2 < 8; ++e2)
        xT[e2] = (kbase + e2 < E_) ? xr[kbase + e2] : 0.f;
    }

    if (s > 0){
      const u32* fp = fbase + ((size_t)((s-1)&(FSLOT_-1))*4 + w)*32*32;
      const u32 expv = (u32)s;
      for (;;){
        u32 v = aload32(fp + (size_t)(lane & 31)*32);
        if (__ballot(v == expv) == ~0ull) break;
      }
      asm volatile("" ::: "memory");
    }

    const int par = s & 1;
    const u64* hap = (const u64*)(hx + (size_t)par*(B_*H_) + (size_t)(m0 + l16)*H_);
    u64 hq[32];
#pragma unroll
    for (int kb = 0; kb < 16; ++kb){
      hq[2*kb]   = aload64(hap + kb*8 + quad*2);
      hq[2*kb+1] = aload64(hap + kb*8 + quad*2 + 1);
    }
#pragma unroll
    for (int kb = 0; kb < 16; ++kb){
      H8 ha;
      ha.q[0] = hq[2*kb];
      ha.q[1] = hq[2*kb+1];
      int uq = kb*4 + quad;
#pragma unroll
      for (int g = 0; g < 4; ++g){
        f16x8 b = *(const f16x8*)&Wh[(g*16+l16)*512 + ((uq ^ (l16&7)))*8];
        acc[g] = __builtin_amdgcn_mfma_f32_16x16x32_f16(ha.v, b, acc[g],0,0,0);
      }
    }

    f16* hn = hx + (size_t)(1-par)*(B_*H_);
#pragma unroll
    for (int r = 0; r < 4; ++r){
      int m = m0 + quad*4 + r;
      float zi = acc[0][r] + bz[0];
      float zf = acc[1][r] + bz[1];
      float zg = acc[2][r] + bz[2];
      float zo = acc[3][r] + bz[3];
      float ig = sigf(zi), fg = sigf(zf), gg = tanhf_(zg), og = sigf(zo);
      float cnew = fg*cpr[r] + ig*gg;
      float hnew = og*tanhf_(cnew);
      bool mk = t < lm[r];
      float hsel = mk ? hnew : hprev[r];
      cpr[r] = mk ? cnew : cpr[r];
      hprev[r] = hsel;
      FU cv; cv.f = (f16)hsel;
      int other = __shfl_down((int)cv.s, 1);
      if ((l16 & 1) == 0)
        astore32((u32*)(hn + (size_t)m*H_ + j), (u32)cv.s | ((u32)other << 16));
    }
    asm volatile("s_waitcnt vmcnt(0)" ::: "memory");
    if (lane == 0)
      astore32(fbase + (((size_t)(s&(FSLOT_-1))*4 + w)*32 + jb)*32, (u32)(s+1));

#pragma unroll
    for (int r = 0; r < 4; ++r){
      int m = m0 + quad*4 + r;
      FU cv; cv.f = (f16)hprev[r];
      int other = __shfl_down((int)cv.s, 1);
      if ((l16 & 1) == 0)
        *(u32*)(outcat + ((size_t)t*B_ + m)*D1_ + dir*H_ + j) = (u32)cv.s | ((u32)other << 16);
    }
  }
}

// ---------------- phase C recurrence: layer-1 reverse over one CH-step chunk ----------------
// grid (2,32) = 64 blocks. R8 structure: Z prefetch before the poll (dead-time
// placement), padded flags, batch h-loads.

__global__ __launch_bounds__(256, 1) void k_phaseCrec(
    const f16* __restrict__ Z1c, const f16* __restrict__ w1h,
    const int* __restrict__ len,
    f16* __restrict__ hx1, float* __restrict__ cstate, float* __restrict__ h1f,
    u32* __restrict__ flagsC, int s0, int CH)
{
  __shared__ f16 Wh[64*512];   // 64 KB
  const int half = blockIdx.x, jb = blockIdx.y;
  u32* fbase = flagsC + (size_t)half*(FSLOT_*4*32*32);
  const int tid = threadIdx.x;
  const int w = tid>>6, lane = tid&63, quad = lane>>4, l16 = lane&15;
  const int j0 = jb*16;
  const int m0 = half*64 + w*16;

  for (int u = tid; u < 4096; u += 256){
    int lrr = u>>6, uc = u&63;
    int g = lrr>>4, i = lrr&15;
    *(uint4*)&Wh[lrr*512 + (uc ^ (i&7))*8] =
        *(const uint4*)(w1h + ((size_t)(g*H_ + j0 + i))*H_ + uc*8);
  }
  __syncthreads();

  const int j = j0 + l16;
  float hprev[4], cpr[4]; int lm[4];
#pragma unroll
  for (int r = 0; r < 4; ++r){
    int m = m0 + quad*4 + r;
    lm[r] = len[m];
    cpr[r] = cstate[(size_t)m*H_ + j];
    hprev[r] = (float)hx1[(size_t)(s0 & 1)*(B_*H_) + (size_t)m*H_ + j];
  }

  for (int sl = 0; sl < CH; ++sl){
    const int s = s0 + sl;
    const int t = S_-1-s;
    const int zrow = CH-1-sl;

    // --- prefetch Z rows (h-independent; overlaps the wait) ---
    float zv[4][4];
#pragma unroll
    for (int g = 0; g < 4; ++g)
#pragma unroll
      for (int r = 0; r < 4; ++r)
        zv[g][r] = (float)Z1c[((size_t)zrow*B_ + m0 + quad*4 + r)*G_ + g*H_ + j];

    if (s > 0){
      const u32* fp = fbase + ((size_t)((s-1)&(FSLOT_-1))*4 + w)*32*32;
      const u32 expv = (u32)s;
      for (;;){
        u32 v = aload32(fp + (size_t)(lane & 31)*32);
        if (__ballot(v == expv) == ~0ull) break;
      }
      asm volatile("" ::: "memory");
    }

    // --- h @ Whh1^T (K=512): batch-issue loads, then MFMA ---
    const int par = s & 1;
    const u64* hap = (const u64*)(hx1 + (size_t)par*(B_*H_) + (size_t)(m0 + l16)*H_);
    f32x4 z4 = {0.f,0.f,0.f,0.f};
    f32x4 acc[4] = {z4,z4,z4,z4};
    u64 hq[32];
#pragma unroll
    for (int kb = 0; kb < 16; ++kb){
      hq[2*kb]   = aload64(hap + kb*8 + quad*2);
      hq[2*kb+1] = aload64(hap + kb*8 + quad*2 + 1);
    }
#pragma unroll
    for (int kb = 0; kb < 16; ++kb){
      H8 ha;
      ha.q[0] = hq[2*kb];
      ha.q[1] = hq[2*kb+1];
      int uq = kb*4 + quad;
#pragma unroll
      for (int g = 0; g < 4; ++g){
        f16x8 b = *(const f16x8*)&Wh[(g*16+l16)*512 + ((uq ^ (l16&7)))*8];
        acc[g] = __builtin_amdgcn_mfma_f32_16x16x32_f16(ha.v, b, acc[g],0,0,0);
      }
    }

    f16* hn = hx1 + (size_t)(1-par)*(B_*H_);
#pragma unroll
    for (int r = 0; r < 4; ++r){
      int m = m0 + quad*4 + r;
      float zi = acc[0][r] + zv[0][r];
      float zf = acc[1][r] + zv[1][r];
      float zg = acc[2][r] + zv[2][r];
      float zo = acc[3][r] + zv[3][r];
      float ig = sigf(zi), fg = sigf(zf), gg = tanhf_(zg), og = sigf(zo);
      float cnew = fg*cpr[r] + ig*gg;
      float hnew = og*tanhf_(cnew);
      bool mk = t < lm[r];
      float hsel = mk ? hnew : hprev[r];
      cpr[r] = mk ? cnew : cpr[r];
      hprev[r] = hsel;
      FU cv; cv.f = (f16)hsel;
      int other = __shfl_down((int)cv.s, 1);
      if ((l16 & 1) == 0)
        astore32((u32*)(hn + (size_t)m*H_ + j), (u32)cv.s | ((u32)other << 16));
    }
    asm volatile("s_waitcnt vmcnt(0)" ::: "memory");
    if (lane == 0)
      astore32(fbase + (((size_t)(s&(FSLOT_-1))*4 + w)*32 + jb)*32, (u32)(s+1));

    if (t == 0){  // deferred final-state write (consumed by k_final after kernel end)
#pragma unroll
      for (int r = 0; r < 4; ++r)
        h1f[(size_t)(m0 + quad*4 + r)*H_ + j] = hprev[r];
    }
  }

  // persist c across chunk launches (h lives in hx1 parity buffers)
#pragma unroll
  for (int r = 0; r < 4; ++r)
    cstate[(size_t)(m0 + quad*4 + r)*H_ + j] = cpr[r];
}

// ---------------- epilogue: folded FC ----------------

__global__ void k_fold(const float* __restrict__ fc1w, const float* __restrict__ fc1b,
                       const float* __restrict__ fcw,  const float* __restrict__ fcb,
                       float* __restrict__ Mf, float* __restrict__ bf){
  int i = blockIdx.x*blockDim.x + threadIdx.x;
  if (i >= 1024) return;
  int o = i >> 9, h = i & 511;
  float s = 0.f;
  for (int jj = 0; jj < 512; ++jj) s += fcw[o*512 + jj] * fc1w[jj*512 + h];
  Mf[o*512 + h] = s;
  if (h == 0){
    float sb = fcb[o];
    for (int jj = 0; jj < 512; ++jj) sb += fcw[o*512 + jj] * fc1b[jj];
    bf[o] = sb;
  }
}

__global__ void k_final(const float* __restrict__ h1f, const float* __restrict__ Mf,
                        const float* __restrict__ bf, float* __restrict__ out){
  int i = threadIdx.x;
  if (i >= 256) return;
  int b = i >> 1, o = i & 1;
  float s = bf[o];
  const float* hp = h1f + (size_t)b*512;
  const float* mp = Mf + (size_t)o*512;
  for (int h = 0; h < 512; ++h) s += hp[h]*mp[h];
  out[b*2 + o] = s;
}

// ---------------- host ----------------

extern "C" void kernel_launch(void* const* d_in, const int* in_sizes, int n_in,
                              void* d_out, int out_size, void* d_ws, size_t ws_size,
                              hipStream_t stream)
{
  const float* x     = (const float*)d_in[0];
  const float* wih0f = (const float*)d_in[1];
  const float* whh0f = (const float*)d_in[2];
  const float* bih0f = (const float*)d_in[3];
  const float* bhh0f = (const float*)d_in[4];
  const float* wih0r = (const float*)d_in[5];
  const float* whh0r = (const float*)d_in[6];
  const float* bih0r = (const float*)d_in[7];
  const float* bhh0r = (const float*)d_in[8];
  // d_in[9..12] = layer1 forward: dead code (only hT_r of layer1 reaches output)
  const float* wih1r = (const float*)d_in[13];
  const float* whh1r = (const float*)d_in[14];
  const float* bih1r = (const float*)d_in[15];
  const float* bhh1r = (const float*)d_in[16];
  const float* fc1w  = (const float*)d_in[17];
  const float* fc1b  = (const float*)d_in[18];
  const float* fcw   = (const float*)d_in[19];
  const float* fcb   = (const float*)d_in[20];
  float* out = (float*)d_out;

  char* p = (char*)d_ws;
  auto alloc = [&](size_t bytes)->char*{
    char* r = p; p += (bytes + 255) & ~(size_t)255; return r;
  };
  f16* w0fp   = (f16*)alloc((size_t)G_*EP_*2);       // 1.3 MB (contiguous with w0rp
  f16* w0rp   = (f16*)alloc((size_t)G_*EP_*2);       //  -> [G2_][EP_] concat matrix)
  f16* whf    = (f16*)alloc((size_t)G_*H_*2);        // 2 MB
  f16* whr    = (f16*)alloc((size_t)G_*H_*2);
  f16* w1i    = (f16*)alloc((size_t)G_*D1_*2);       // 4 MB
  f16* w1h    = (f16*)alloc((size_t)G_*H_*2);        // 2 MB
  float* bs0  = (float*)alloc((size_t)2*G_*4);       // [G2_] concat bias
  float* bs1r = (float*)alloc(G_*4);
  int*   len  = (int*)alloc(B_*4);
  f16* outcat = (f16*)alloc((size_t)S_*B_*D1_*2);    // 67 MB
  f16* hxA    = (f16*)alloc((size_t)2*2*B_*H_*2);
  f16* hx1    = (f16*)alloc((size_t)2*B_*H_*2);
  float* cstate=(float*)alloc((size_t)B_*H_*4);
  float* h1f  = (float*)alloc((size_t)B_*H_*4);
  float* Mf   = (float*)alloc(2*512*4);
  float* bf   = (float*)alloc(256);
  u32* flagsA = (u32*)alloc((size_t)FA_WORDS_*4);    // 256 KB padded flags
  u32* flagsC = (u32*)alloc((size_t)FC_WORDS_*4);    // 128 KB
  size_t used = (size_t)(p - (char*)d_ws);

  // ---- Xz capacity check: Xz[S*B][G2_] f16 (268MB, aliases Z1c) + xf (21MB)
  const size_t XZ_BYTES = (size_t)S_*B_*G2_*2;
  const size_t XF_BYTES = (size_t)S_*B_*EP_*2;
  f16* Xz = nullptr; f16* xf = nullptr; f16* Z1c; int CH;
  if (used + XZ_BYTES + XF_BYTES + 512 <= ws_size){
    Xz  = (f16*)alloc(XZ_BYTES);
    xf  = (f16*)alloc(XF_BYTES);
    Z1c = Xz;            // phaseA consumes Xz before phaseC writes Z1c
    CH  = 256;           // 256*B*G*2 = 134MB <= 268MB  ✓
  } else {
    CH = 8;
    for (int c = 256; c >= 8; c >>= 1){
      if (used + (size_t)c*B_*G_*2 <= ws_size){ CH = c; break; }
    }
    Z1c = (f16*)alloc((size_t)CH*B_*G_*2);
  }
  const int NC = S_/CH;

  int n;
  n = G_*EP_; k_pad_w<<<(n+255)/256, 256, 0, stream>>>(wih0f, w0fp, G_, E_, EP_);
              k_pad_w<<<(n+255)/256, 256, 0, stream>>>(wih0r, w0rp, G_, E_, EP_);
  n = G_*H_;  k_f32_to_f16<<<(n+255)/256,256,0,stream>>>(whh0f, whf, n);
              k_f32_to_f16<<<(n+255)/256,256,0,stream>>>(whh0r, whr, n);
              k_f32_to_f16<<<(n+255)/256,256,0,stream>>>(whh1r, w1h, n);
  n = G_*D1_; k_f32_to_f16<<<(n+255)/256,256,0,stream>>>(wih1r, w1i, n);
  k_bias<<<8,256,0,stream>>>(bih0f, bhh0f, bs0, G_);
  k_bias<<<8,256,0,stream>>>(bih0r, bhh0r, bs0 + G_, G_);
  k_bias<<<8,256,0,stream>>>(bih1r, bhh1r, bs1r, G_);
  k_len<<<1,128,0,stream>>>(x, len);
  k_init<<<(B_*H_+255)/256,256,0,stream>>>(hxA, hx1, cstate);
  k_zero<<<(FA_WORDS_+255)/256,256,0,stream>>>(flagsA, FA_WORDS_);
  k_zero<<<(FC_WORDS_+255)/256,256,0,stream>>>(flagsC, FC_WORDS_);
  k_fold<<<4,256,0,stream>>>(fc1w, fc1b, fcw, fcb, Mf, bf);

  // ---- Xz precompute: xz[(t*B+m)] = x_f16 @ [Wih_f||Wih_r]^T + [b_f||b_r] ----
  if (Xz){
    n = S_*B_*EP_;
    k_cast_x<<<(n+255)/256, 256, 0, stream>>>(x, xf);
    k_gemm_bt<<<dim3(S_*B_/128, G2_/128), 256, 0, stream>>>(
        xf, w0fp, Xz, bs0, S_*B_, G2_, EP_);
  }

  // ---- phase A: layer-0 fwd+rev, single persistent launch ----
  k_phaseA<<<dim3(2,32,2), 256, 0, stream>>>(
      x, Xz, w0fp, w0rp, whf, whr, bs0, len, hxA, outcat, flagsA);

  // ---- phase C: per chunk, dense Z1 GEMM (128^2 tile) then recurrence ----
  for (int cc = 0; cc < NC; ++cc){
    int t0 = S_ - (cc+1)*CH;     // chunk covers t in [t0, t0+CH), consumed descending
    k_gemm_bt<<<dim3(CH, 16), 256, 0, stream>>>(
        outcat + (size_t)t0*B_*D1_, w1i, Z1c, bs1r, CH*B_, G_, D1_);
    k_phaseCrec<<<dim3(2,32), 256, 0, stream>>>(
        Z1c, w1h, len, hx1, cstate, h1f, flagsC, cc*CH, CH);
  }

  k_final<<<1,256,0,stream>>>(h1f, Mf, bf, out);
}

// Round 13
// 3685.200 us; speedup vs baseline: 1.2702x; 1.0775x over previous
//
#include <hip/hip_runtime.h>

#define B_  128
#define S_  256
#define E_  300
#define EP_ 320
#define H_  512
#define G_  2048   // 4*H
#define D1_ 1024   // 2*H
// padded flags: [grp][slot(4)][wave(4)][jb(32)] x 32 u32 (128B line each)
#define FSLOT_ 4
#define FA_WORDS_ (4*FSLOT_*4*32*32)
#define FC_WORDS_ (2*FSLOT_*4*32*32)

typedef _Float16 f16;
typedef __attribute__((ext_vector_type(8))) _Float16 f16x8;
typedef __attribute__((ext_vector_type(4))) float    f32x4;
typedef unsigned long long u64;
typedef unsigned int u32;

__device__ __forceinline__ float sigf(float x){ return 1.f/(1.f + __expf(-x)); }
__device__ __forceinline__ float tanhf_(float x){
  float e = __expf(-2.f*fabsf(x));
  float t = (1.f - e)/(1.f + e);
  return x < 0.f ? -t : t;
}

// Ledger (us/step, phaseA): R8 padded flags 8.0 (total 4108); R11 128^2 gemm
// (total 3978, phaseC step ~5.7); R12 full-Xz precompute FELL BACK (ws<371MB,
// total unchanged) -> Xz idea untested. R13: CHUNKED Xz - phaseA split into
// NCA chunk launches (like phaseC), each preceded by 2 small dense GEMMs
// computing the window's x-part. Removes the 2.3us/step in-step x-GEMM from
// the serial chain at CHA*1MB memory instead of 268MB. c persists in cstateA;
// h persists in hxA parity buffers; flags use global s. Fallback = exact R11.
__device__ __forceinline__ u64 aload64(const u64* p){
  return __hip_atomic_load((u64*)p, __ATOMIC_RELAXED, __HIP_MEMORY_SCOPE_AGENT);
}
__device__ __forceinline__ u32 aload32(const u32* p){
  return __hip_atomic_load((u32*)p, __ATOMIC_RELAXED, __HIP_MEMORY_SCOPE_AGENT);
}
__device__ __forceinline__ void astore32(u32* p, u32 v){
  __hip_atomic_store(p, v, __ATOMIC_RELAXED, __HIP_MEMORY_SCOPE_AGENT);
}
union H8 { u64 q[2]; f16x8 v; };
union FU { f16 f; unsigned short s; };

// ---------------- setup kernels ----------------

__global__ void k_f32_to_f16(const float* __restrict__ s, f16* __restrict__ d, int n){
  int i = blockIdx.x*blockDim.x + threadIdx.x;
  if (i < n) d[i] = (f16)s[i];
}

__global__ void k_pad_w(const float* __restrict__ s, f16* __restrict__ d, int rows, int ks, int kd){
  int i = blockIdx.x*blockDim.x + threadIdx.x;
  if (i >= rows*kd) return;
  int r = i/kd, k = i - r*kd;
  d[i] = (k < ks) ? (f16)s[(size_t)r*ks + k] : (f16)0.f;
}

// x[B,S,E] f32 -> xf[(t*B+m)*EP_] f16, zero-padded to EP_
__global__ void k_cast_x(const float* __restrict__ x, f16* __restrict__ xf){
  int i = blockIdx.x*blockDim.x + threadIdx.x;
  if (i >= S_*B_*EP_) return;
  int e = i % EP_; int rm = i / EP_;
  int m = rm % B_; int t = rm / B_;
  xf[i] = (e < E_) ? (f16)x[((size_t)m*S_ + t)*E_ + e] : (f16)0.f;
}

__global__ void k_bias(const float* __restrict__ a, const float* __restrict__ b,
                       float* __restrict__ d, int n){
  int i = blockIdx.x*blockDim.x + threadIdx.x;
  if (i < n) d[i] = a[i] + b[i];
}

__global__ void k_len(const float* __restrict__ x, int* __restrict__ len){
  int b = threadIdx.x;
  if (b < B_){
    int v = (int)x[((size_t)b*S_ + (S_-1))*E_];
    len[b] = v > S_ ? S_ : v;
  }
}

__global__ void k_zero(u32* __restrict__ p, int n){
  int i = blockIdx.x*blockDim.x + threadIdx.x;
  if (i < n) p[i] = 0u;
}

// hxA: [dir][parity][B*H], hx1: [parity][B*H]; parity-0 = h0 = 1.
// cstate (C) and cstateA (A, both dirs) = 1.
__global__ void k_init(f16* hxA, f16* hx1, float* cstate, float* cstateA){
  int i = blockIdx.x*blockDim.x + threadIdx.x;
  if (i < B_*H_){
    hxA[i] = (f16)1.f;                // dir0 par0
    hxA[2*B_*H_ + i] = (f16)1.f;      // dir1 par0
    hx1[i] = (f16)1.f;                // par0
    cstate[i] = 1.f;
    cstateA[i] = 1.f;                 // dir0
    cstateA[B_*H_ + i] = 1.f;         // dir1
  }
}

// ---------------- GEMM: C[M,N] = A[M,K] @ B[N,K]^T + bias (f16 in/out, fp32 acc) ----
// 128x128 tile, BK=32, 256 thr (4 waves, 2x2 quadrants of 64x64, 4x4 MFMA accs
// each). Staging via global_load_lds width=16 into LINEAR row-major LDS
// [row][32]. M multiple of 128, N mult of 128, K mult of 32 -> no guards.

__global__ __launch_bounds__(256) void k_gemm_bt(
    const f16* __restrict__ A, const f16* __restrict__ Bm,
    f16* __restrict__ C, const float* __restrict__ bias,
    int M, int N, int K)
{
  __shared__ f16 As[128*32];   // 8 KB
  __shared__ f16 Bs[128*32];   // 8 KB
  const int m0 = blockIdx.x*128, n0 = blockIdx.y*128;
  const int tid = threadIdx.x;
  const int w = tid>>6, lane = tid&63, quad = lane>>4, l16 = lane&15;
  const int wm = (w&1)*64, wn = (w>>1)*64;   // wave's 64x64 quadrant
  const int srow = w*32 + (lane>>2);
  const int scol = (lane&3)*8;
  const f16* Ap  = A  + (size_t)(m0 + srow)*K + scol;
  const f16* Bp  = Bm + (size_t)(n0 + srow)*K + scol;
  const f16* Ap2 = Ap + (size_t)16*K;
  const f16* Bp2 = Bp + (size_t)16*K;
  f16* ldsA  = &As[(w*32)*32];       // wave-uniform bases
  f16* ldsA2 = &As[(w*32+16)*32];
  f16* ldsB  = &Bs[(w*32)*32];
  f16* ldsB2 = &Bs[(w*32+16)*32];
  f32x4 z4 = {0.f,0.f,0.f,0.f};
  f32x4 acc[4][4];
#pragma unroll
  for (int mi = 0; mi < 4; ++mi)
#pragma unroll
    for (int ni = 0; ni < 4; ++ni) acc[mi][ni] = z4;

  for (int k0 = 0; k0 < K; k0 += 32){
    __builtin_amdgcn_global_load_lds(
        (const __attribute__((address_space(1))) void*)(Ap + k0),
        (__attribute__((address_space(3))) void*)ldsA, 16, 0, 0);
    __builtin_amdgcn_global_load_lds(
        (const __attribute__((address_space(1))) void*)(Ap2 + k0),
        (__attribute__((address_space(3))) void*)ldsA2, 16, 0, 0);
    __builtin_amdgcn_global_load_lds(
        (const __attribute__((address_space(1))) void*)(Bp + k0),
        (__attribute__((address_space(3))) void*)ldsB, 16, 0, 0);
    __builtin_amdgcn_global_load_lds(
        (const __attribute__((address_space(1))) void*)(Bp2 + k0),
        (__attribute__((address_space(3))) void*)ldsB2, 16, 0, 0);
    asm volatile("s_waitcnt vmcnt(0)" ::: "memory");
    __syncthreads();
    f16x8 a[4], b[4];
#pragma unroll
    for (int mi = 0; mi < 4; ++mi)
      a[mi] = *(const f16x8*)&As[(wm + mi*16 + l16)*32 + quad*8];
#pragma unroll
    for (int ni = 0; ni < 4; ++ni)
      b[ni] = *(const f16x8*)&Bs[(wn + ni*16 + l16)*32 + quad*8];
#pragma unroll
    for (int mi = 0; mi < 4; ++mi)
#pragma unroll
      for (int ni = 0; ni < 4; ++ni)
        acc[mi][ni] = __builtin_amdgcn_mfma_f32_16x16x32_f16(a[mi], b[ni], acc[mi][ni],0,0,0);
    __syncthreads();
  }
#pragma unroll
  for (int mi = 0; mi < 4; ++mi)
#pragma unroll
    for (int ni = 0; ni < 4; ++ni){
      int col = n0 + wn + ni*16 + l16;
      float bz = bias[col];
#pragma unroll
      for (int r = 0; r < 4; ++r){
        int row = m0 + wm + mi*16 + quad*4 + r;
        C[(size_t)row*N + col] = (f16)(acc[mi][ni][r] + bz);
      }
    }
}

// ---------------- phase A (Xz path): one CHA-step chunk, x-part precomputed ----------------
// grid (2,32,2). Step shaped like phaseC: zv loads (bias folded) in poll dead
// time -> poll -> batch h-loads -> MFMA -> gates -> vmcnt(0) -> flag.
// Xz = dir? Xzr : Xzf, laid out [zrow][B][G]; fwd zrow=sl, rev zrow=CHA-1-sl.
// State across chunks: h in hxA parity bufs, c in cstateA, flags global-s.

__global__ __launch_bounds__(256, 1) void k_phaseA_xz(
    const f16* __restrict__ Xzf, const f16* __restrict__ Xzr,
    const f16* __restrict__ whf, const f16* __restrict__ whr,
    const int* __restrict__ len,
    f16* __restrict__ hxA, float* __restrict__ cstateA,
    f16* __restrict__ outcat, u32* __restrict__ flagsA,
    int s0, int CHA)
{
  __shared__ f16 Wh[64*512];   // 64 KB
  const int half = blockIdx.x, jb = blockIdx.y, dir = blockIdx.z;
  const f16* whh = dir ? whr : whf;
  const f16* Xz  = dir ? Xzr : Xzf;
  f16* hx = hxA + (size_t)dir*(2*B_*H_);
  float* cst = cstateA + (size_t)dir*(B_*H_);
  u32* fbase = flagsA + (size_t)(dir*2 + half)*(FSLOT_*4*32*32);
  const int tid = threadIdx.x;
  const int w = tid>>6, lane = tid&63, quad = lane>>4, l16 = lane&15;
  const int j0 = jb*16;
  const int m0 = half*64 + w*16;

  for (int u = tid; u < 4096; u += 256){
    int lrr = u>>6, uc = u&63;
    int g = lrr>>4, i = lrr&15;
    *(uint4*)&Wh[lrr*512 + (uc ^ (i&7))*8] =
        *(const uint4*)(whh + ((size_t)(g*H_ + j0 + i))*H_ + uc*8);
  }
  __syncthreads();

  const int j = j0 + l16;
  float hprev[4], cpr[4]; int lm[4];
#pragma unroll
  for (int r = 0; r < 4; ++r){
    int m = m0 + quad*4 + r;
    lm[r] = len[m];
    cpr[r] = cst[(size_t)m*H_ + j];
    hprev[r] = (float)hx[(size_t)(s0 & 1)*(B_*H_) + (size_t)m*H_ + j];
  }

  for (int sl = 0; sl < CHA; ++sl){
    const int s = s0 + sl;
    const int t = dir ? (S_-1-s) : s;
    const int zrow = dir ? (CHA-1-sl) : sl;

    // --- zv loads (bias folded); poll dead-time placement ---
    const f16* zr = Xz + ((size_t)zrow*B_)*G_;
    float zvv[4][4];
#pragma unroll
    for (int g = 0; g < 4; ++g)
#pragma unroll
      for (int r = 0; r < 4; ++r)
        zvv[g][r] = (float)zr[(size_t)(m0 + quad*4 + r)*G_ + g*H_ + j];

    if (s > 0){
      const u32* fp = fbase + ((size_t)((s-1)&(FSLOT_-1))*4 + w)*32*32;
      const u32 expv = (u32)s;
      for (;;){
        u32 v = aload32(fp + (size_t)(lane & 31)*32);
        if (__ballot(v == expv) == ~0ull) break;
      }
      asm volatile("" ::: "memory");
    }

    const int par = s & 1;
    const u64* hap = (const u64*)(hx + (size_t)par*(B_*H_) + (size_t)(m0 + l16)*H_);
    f32x4 z4 = {0.f,0.f,0.f,0.f};
    f32x4 acc[4] = {z4,z4,z4,z4};
    u64 hq[32];
#pragma unroll
    for (int kb = 0; kb < 16; ++kb){
      hq[2*kb]   = aload64(hap + kb*8 + quad*2);
      hq[2*kb+1] = aload64(hap + kb*8 + quad*2 + 1);
    }
#pragma unroll
    for (int kb = 0; kb < 16; ++kb){
      H8 ha;
      ha.q[0] = hq[2*kb];
      ha.q[1] = hq[2*kb+1];
      int uq = kb*4 + quad;
#pragma unroll
      for (int g = 0; g < 4; ++g){
        f16x8 b = *(const f16x8*)&Wh[(g*16+l16)*512 + ((uq ^ (l16&7)))*8];
        acc[g] = __builtin_amdgcn_mfma_f32_16x16x32_f16(ha.v, b, acc[g],0,0,0);
      }
    }

    f16* hn = hx + (size_t)(1-par)*(B_*H_);
#pragma unroll
    for (int r = 0; r < 4; ++r){
      int m = m0 + quad*4 + r;
      float zi = acc[0][r] + zvv[0][r];
      float zf = acc[1][r] + zvv[1][r];
      float zg = acc[2][r] + zvv[2][r];
      float zo = acc[3][r] + zvv[3][r];
      float ig = sigf(zi), fg = sigf(zf), gg = tanhf_(zg), og = sigf(zo);
      float cnew = fg*cpr[r] + ig*gg;
      float hnew = og*tanhf_(cnew);
      bool mk = t < lm[r];
      float hsel = mk ? hnew : hprev[r];
      cpr[r] = mk ? cnew : cpr[r];
      hprev[r] = hsel;
      FU cv; cv.f = (f16)hsel;
      int other = __shfl_down((int)cv.s, 1);
      if ((l16 & 1) == 0)
        astore32((u32*)(hn + (size_t)m*H_ + j), (u32)cv.s | ((u32)other << 16));
    }
    asm volatile("s_waitcnt vmcnt(0)" ::: "memory");
    if (lane == 0)
      astore32(fbase + (((size_t)(s&(FSLOT_-1))*4 + w)*32 + jb)*32, (u32)(s+1));

#pragma unroll
    for (int r = 0; r < 4; ++r){
      int m = m0 + quad*4 + r;
      FU cv; cv.f = (f16)hprev[r];
      int other = __shfl_down((int)cv.s, 1);
      if ((l16 & 1) == 0)
        *(u32*)(outcat + ((size_t)t*B_ + m)*D1_ + dir*H_ + j) = (u32)cv.s | ((u32)other << 16);
    }
  }

  // persist c across chunk launches
#pragma unroll
  for (int r = 0; r < 4; ++r)
    cst[(size_t)(m0 + quad*4 + r)*H_ + j] = cpr[r];
}

// ---------------- phase A fallback: exact R11 persistent kernel ----------------

__global__ __launch_bounds__(256, 1) void k_phaseA(
    const float* __restrict__ x,
    const f16* __restrict__ w0f, const f16* __restrict__ w0r,
    const f16* __restrict__ whf, const f16* __restrict__ whr,
    const float* __restrict__ bs0, const int* __restrict__ len,
    f16* __restrict__ hxA, f16* __restrict__ outcat,
    u32* __restrict__ flagsA)
{
  __shared__ f16 Wh[64*512];   // 64 KB
  __shared__ f16 Wi[64*320];   // 40 KB
  const int half = blockIdx.x, jb = blockIdx.y, dir = blockIdx.z;
  const f16* wih = dir ? w0r : w0f;
  const f16* whh = dir ? whr : whf;
  const float* bias = bs0 + dir*G_;
  f16* hx = hxA + (size_t)dir*(2*B_*H_);
  u32* fbase = flagsA + (size_t)(dir*2 + half)*(FSLOT_*4*32*32);
  const int tid = threadIdx.x;
  const int w = tid>>6, lane = tid&63, quad = lane>>4, l16 = lane&15;
  const int j0 = jb*16;
  const int m0 = half*64 + w*16;

  for (int u = tid; u < 4096; u += 256){
    int lrr = u>>6, uc = u&63;
    int g = lrr>>4, i = lrr&15;
    *(uint4*)&Wh[lrr*512 + (uc ^ (i&7))*8] =
        *(const uint4*)(whh + ((size_t)(g*H_ + j0 + i))*H_ + uc*8);
  }
  for (int u = tid; u < 2560; u += 256){
    int row = u/40, c = u - row*40;
    int g = row>>4, i = row&15;
    *(uint4*)&Wi[row*320 + (c ^ (i&7))*8] =
        *(const uint4*)(wih + ((size_t)(g*H_ + j0 + i))*EP_ + c*8);
  }
  __syncthreads();

  const int j = j0 + l16;
  float bz[4], hprev[4], cpr[4]; int lm[4];
#pragma unroll
  for (int g = 0; g < 4; ++g) bz[g] = bias[g*H_ + j];
#pragma unroll
  for (int r = 0; r < 4; ++r){ hprev[r] = 1.f; cpr[r] = 1.f; lm[r] = len[m0 + quad*4 + r]; }
  const size_t xrowbase = (size_t)(m0 + l16)*S_;

  float4 xA[9], xB[9]; float xT[8];
  {
    const int t0 = dir ? (S_-1) : 0;
    const float* xr = x + (xrowbase + t0)*E_;
#pragma unroll
    for (int kb = 0; kb < 9; ++kb){
      xA[kb] = *(const float4*)(xr + kb*32 + quad*8);
      xB[kb] = *(const float4*)(xr + kb*32 + quad*8 + 4);
    }
    int kbase = 288 + quad*8;
#pragma unroll
    for (int e2 = 0; e2 < 8; ++e2)
      xT[e2] = (kbase + e2 < E_) ? xr[kbase + e2] : 0.f;
  }

  for (int s = 0; s < S_; ++s){
    const int t = dir ? (S_-1-s) : s;
    f32x4 z4 = {0.f,0.f,0.f,0.f};
    f32x4 acc[4] = {z4,z4,z4,z4};

#pragma unroll
    for (int kb = 0; kb < 9; ++kb){
      f16x8 a;
      a[0]=(f16)xA[kb].x; a[1]=(f16)xA[kb].y; a[2]=(f16)xA[kb].z; a[3]=(f16)xA[kb].w;
      a[4]=(f16)xB[kb].x; a[5]=(f16)xB[kb].y; a[6]=(f16)xB[kb].z; a[7]=(f16)xB[kb].w;
      int c = (kb*4 + quad) ^ (l16 & 7);
#pragma unroll
      for (int g = 0; g < 4; ++g){
        f16x8 b = *(const f16x8*)&Wi[(g*16+l16)*320 + c*8];
        acc[g] = __builtin_amdgcn_mfma_f32_16x16x32_f16(a, b, acc[g],0,0,0);
      }
    }
    {
      f16x8 a;
#pragma unroll
      for (int e2 = 0; e2 < 8; ++e2) a[e2] = (f16)xT[e2];
      int c = (36 + quad) ^ (l16 & 7);
#pragma unroll
      for (int g = 0; g < 4; ++g){
        f16x8 b = *(const f16x8*)&Wi[(g*16+l16)*320 + c*8];
        acc[g] = __builtin_amdgcn_mfma_f32_16x16x32_f16(a, b, acc[g],0,0,0);
      }
    }

    if (s+1 < S_){
      const int tn = dir ? (S_-2-s) : (s+1);
      const float* xr = x + (xrowbase + tn)*E_;
#pragma unroll
      for (int kb = 0; kb < 9; ++kb){
        xA[kb] = *(const float4*)(xr + kb*32 + quad*8);
        xB[kb] = *(const float4*)(xr + kb*32 + quad*8 + 4);
      }
      int kbase = 288 + quad*8;
#pragma unroll
      for (int e2 = 0; e2 < 8; ++e2)
        xT[e2] = (kbase + e2 < E_) ? xr[kbase + e2] : 0.f;
    }

    if (s > 0){
      const u32* fp = fbase + ((size_t)((s-1)&(FSLOT_-1))*4 + w)*32*32;
      const u32 expv = (u32)s;
      for (;;){
        u32 v = aload32(fp + (size_t)(lane & 31)*32);
        if (__ballot(v == expv) == ~0ull) break;
      }
      asm volatile("" ::: "memory");
    }

    const int par = s & 1;
    const u64* hap = (const u64*)(hx + (size_t)par*(B_*H_) + (size_t)(m0 + l16)*H_);
    u64 hq[32];
#pragma unroll
    for (int kb = 0; kb < 16; ++kb){
      hq[2*kb]   = aload64(hap + kb*8 + quad*2);
      hq[2*kb+1] = aload64(hap + kb*8 + quad*2 + 1);
    }
#pragma unroll
    for (int kb = 0; kb < 16; ++kb){
      H8 ha;
      ha.q[0] = hq[2*kb];
      ha.q[1] = hq[2*kb+1];
      int uq = kb*4 + quad;
#pragma unroll
      for (int g = 0; g < 4; ++g){
        f16x8 b = *(const f16x8*)&Wh[(g*16+l16)*512 + ((uq ^ (l16&7)))*8];
        acc[g] = __builtin_amdgcn_mfma_f32_16x16x32_f16(ha.v, b, acc[g],0,0,0);
      }
    }

    f16* hn = hx + (size_t)(1-par)*(B_*H_);
#pragma unroll
    for (int r = 0; r < 4; ++r){
      int m = m0 + quad*4 + r;
      float zi = acc[0][r] + bz[0];
      float zf = acc[1][r] + bz[1];
      float zg = acc[2][r] + bz[2];
      float zo = acc[3][r] + bz[3];
      float ig = sigf(zi), fg = sigf(zf), gg = tanhf_(zg), og = sigf(zo);
      float cnew = fg*cpr[r] + ig*gg;
      float hnew = og*tanhf_(cnew);
      bool mk = t < lm[r];
      float hsel = mk ? hnew : hprev[r];
      cpr[r] = mk ? cnew : cpr[r];
      hprev[r] = hsel;
      FU cv; cv.f = (f16)hsel;
      int other = __shfl_down((int)cv.s, 1);
      if ((l16 & 1) == 0)
        astore32((u32*)(hn + (size_t)m*H_ + j), (u32)cv.s | ((u32)other << 16));
    }
    asm volatile("s_waitcnt vmcnt(0)" ::: "memory");
    if (lane == 0)
      astore32(fbase + (((size_t)(s&(FSLOT_-1))*4 + w)*32 + jb)*32, (u32)(s+1));

#pragma unroll
    for (int r = 0; r < 4; ++r){
      int m = m0 + quad*4 + r;
      FU cv; cv.f = (f16)hprev[r];
      int other = __shfl_down((int)cv.s, 1);
      if ((l16 & 1) == 0)
        *(u32*)(outcat + ((size_t)t*B_ + m)*D1_ + dir*H_ + j) = (u32)cv.s | ((u32)other << 16);
    }
  }
}

// ---------------- phase C recurrence: layer-1 reverse over one CH-step chunk ----------------

__global__ __launch_bounds__(256, 1) void k_phaseCrec(
    const f16* __restrict__ Z1c, const f16* __restrict__ w1h,
    const int* __restrict__ len,
    f16* __restrict__ hx1, float* __restrict__ cstate, float* __restrict__ h1f,
    u32* __restrict__ flagsC, int s0, int CH)
{
  __shared__ f16 Wh[64*512];   // 64 KB
  const int half = blockIdx.x, jb = blockIdx.y;
  u32* fbase = flagsC + (size_t)half*(FSLOT_*4*32*32);
  const int tid = threadIdx.x;
  const int w = tid>>6, lane = tid&63, quad = lane>>4, l16 = lane&15;
  const int j0 = jb*16;
  const int m0 = half*64 + w*16;

  for (int u = tid; u < 4096; u += 256){
    int lrr = u>>6, uc = u&63;
    int g = lrr>>4, i = lrr&15;
    *(uint4*)&Wh[lrr*512 + (uc ^ (i&7))*8] =
        *(const uint4*)(w1h + ((size_t)(g*H_ + j0 + i))*H_ + uc*8);
  }
  __syncthreads();

  const int j = j0 + l16;
  float hprev[4], cpr[4]; int lm[4];
#pragma unroll
  for (int r = 0; r < 4; ++r){
    int m = m0 + quad*4 + r;
    lm[r] = len[m];
    cpr[r] = cstate[(size_t)m*H_ + j];
    hprev[r] = (float)hx1[(size_t)(s0 & 1)*(B_*H_) + (size_t)m*H_ + j];
  }

  for (int sl = 0; sl < CH; ++sl){
    const int s = s0 + sl;
    const int t = S_-1-s;
    const int zrow = CH-1-sl;

    float zv[4][4];
#pragma unroll
    for (int g = 0; g < 4; ++g)
#pragma unroll
      for (int r = 0; r < 4; ++r)
        zv[g][r] = (float)Z1c[((size_t)zrow*B_ + m0 + quad*4 + r)*G_ + g*H_ + j];

    if (s > 0){
      const u32* fp = fbase + ((size_t)((s-1)&(FSLOT_-1))*4 + w)*32*32;
      const u32 expv = (u32)s;
      for (;;){
        u32 v = aload32(fp + (size_t)(lane & 31)*32);
        if (__ballot(v == expv) == ~0ull) break;
      }
      asm volatile("" ::: "memory");
    }

    const int par = s & 1;
    const u64* hap = (const u64*)(hx1 + (size_t)par*(B_*H_) + (size_t)(m0 + l16)*H_);
    f32x4 z4 = {0.f,0.f,0.f,0.f};
    f32x4 acc[4] = {z4,z4,z4,z4};
    u64 hq[32];
#pragma unroll
    for (int kb = 0; kb < 16; ++kb){
      hq[2*kb]   = aload64(hap + kb*8 + quad*2);
      hq[2*kb+1] = aload64(hap + kb*8 + quad*2 + 1);
    }
#pragma unroll
    for (int kb = 0; kb < 16; ++kb){
      H8 ha;
      ha.q[0] = hq[2*kb];
      ha.q[1] = hq[2*kb+1];
      int uq = kb*4 + quad;
#pragma unroll
      for (int g = 0; g < 4; ++g){
        f16x8 b = *(const f16x8*)&Wh[(g*16+l16)*512 + ((uq ^ (l16&7)))*8];
        acc[g] = __builtin_amdgcn_mfma_f32_16x16x32_f16(ha.v, b, acc[g],0,0,0);
      }
    }

    f16* hn = hx1 + (size_t)(1-par)*(B_*H_);
#pragma unroll
    for (int r = 0; r < 4; ++r){
      int m = m0 + quad*4 + r;
      float zi = acc[0][r] + zv[0][r];
      float zf = acc[1][r] + zv[1][r];
      float zg = acc[2][r] + zv[2][r];
      float zo = acc[3][r] + zv[3][r];
      float ig = sigf(zi), fg = sigf(zf), gg = tanhf_(zg), og = sigf(zo);
      float cnew = fg*cpr[r] + ig*gg;
      float hnew = og*tanhf_(cnew);
      bool mk = t < lm[r];
      float hsel = mk ? hnew : hprev[r];
      cpr[r] = mk ? cnew : cpr[r];
      hprev[r] = hsel;
      FU cv; cv.f = (f16)hsel;
      int other = __shfl_down((int)cv.s, 1);
      if ((l16 & 1) == 0)
        astore32((u32*)(hn + (size_t)m*H_ + j), (u32)cv.s | ((u32)other << 16));
    }
    asm volatile("s_waitcnt vmcnt(0)" ::: "memory");
    if (lane == 0)
      astore32(fbase + (((size_t)(s&(FSLOT_-1))*4 + w)*32 + jb)*32, (u32)(s+1));

    if (t == 0){
#pragma unroll
      for (int r = 0; r < 4; ++r)
        h1f[(size_t)(m0 + quad*4 + r)*H_ + j] = hprev[r];
    }
  }

#pragma unroll
  for (int r = 0; r < 4; ++r)
    cstate[(size_t)(m0 + quad*4 + r)*H_ + j] = cpr[r];
}

// ---------------- epilogue: folded FC ----------------

__global__ void k_fold(const float* __restrict__ fc1w, const float* __restrict__ fc1b,
                       const float* __restrict__ fcw,  const float* __restrict__ fcb,
                       float* __restrict__ Mf, float* __restrict__ bf){
  int i = blockIdx.x*blockDim.x + threadIdx.x;
  if (i >= 1024) return;
  int o = i >> 9, h = i & 511;
  float s = 0.f;
  for (int jj = 0; jj < 512; ++jj) s += fcw[o*512 + jj] * fc1w[jj*512 + h];
  Mf[o*512 + h] = s;
  if (h == 0){
    float sb = fcb[o];
    for (int jj = 0; jj < 512; ++jj) sb += fcw[o*512 + jj] * fc1b[jj];
    bf[o] = sb;
  }
}

__global__ void k_final(const float* __restrict__ h1f, const float* __restrict__ Mf,
                        const float* __restrict__ bf, float* __restrict__ out){
  int i = threadIdx.x;
  if (i >= 256) return;
  int b = i >> 1, o = i & 1;
  float s = bf[o];
  const float* hp = h1f + (size_t)b*512;
  const float* mp = Mf + (size_t)o*512;
  for (int h = 0; h < 512; ++h) s += hp[h]*mp[h];
  out[b*2 + o] = s;
}

// ---------------- host ----------------

extern "C" void kernel_launch(void* const* d_in, const int* in_sizes, int n_in,
                              void* d_out, int out_size, void* d_ws, size_t ws_size,
                              hipStream_t stream)
{
  const float* x     = (const float*)d_in[0];
  const float* wih0f = (const float*)d_in[1];
  const float* whh0f = (const float*)d_in[2];
  const float* bih0f = (const float*)d_in[3];
  const float* bhh0f = (const float*)d_in[4];
  const float* wih0r = (const float*)d_in[5];
  const float* whh0r = (const float*)d_in[6];
  const float* bih0r = (const float*)d_in[7];
  const float* bhh0r = (const float*)d_in[8];
  // d_in[9..12] = layer1 forward: dead code (only hT_r of layer1 reaches output)
  const float* wih1r = (const float*)d_in[13];
  const float* whh1r = (const float*)d_in[14];
  const float* bih1r = (const float*)d_in[15];
  const float* bhh1r = (const float*)d_in[16];
  const float* fc1w  = (const float*)d_in[17];
  const float* fc1b  = (const float*)d_in[18];
  const float* fcw   = (const float*)d_in[19];
  const float* fcb   = (const float*)d_in[20];
  float* out = (float*)d_out;

  char* p = (char*)d_ws;
  auto alloc = [&](size_t bytes)->char*{
    char* r = p; p += (bytes + 255) & ~(size_t)255; return r;
  };
  f16* w0fp   = (f16*)alloc((size_t)G_*EP_*2);       // 1.3 MB
  f16* w0rp   = (f16*)alloc((size_t)G_*EP_*2);
  f16* whf    = (f16*)alloc((size_t)G_*H_*2);        // 2 MB
  f16* whr    = (f16*)alloc((size_t)G_*H_*2);
  f16* w1i    = (f16*)alloc((size_t)G_*D1_*2);       // 4 MB
  f16* w1h    = (f16*)alloc((size_t)G_*H_*2);        // 2 MB
  float* bs0  = (float*)alloc((size_t)2*G_*4);
  float* bs1r = (float*)alloc(G_*4);
  int*   len  = (int*)alloc(B_*4);
  f16* outcat = (f16*)alloc((size_t)S_*B_*D1_*2);    // 67 MB
  f16* hxA    = (f16*)alloc((size_t)2*2*B_*H_*2);
  f16* hx1    = (f16*)alloc((size_t)2*B_*H_*2);
  float* cstate =(float*)alloc((size_t)B_*H_*4);
  float* cstateA=(float*)alloc((size_t)2*B_*H_*4);   // 512 KB (phaseA chunks)
  float* h1f  = (float*)alloc((size_t)B_*H_*4);
  float* Mf   = (float*)alloc(2*512*4);
  float* bf   = (float*)alloc(256);
  u32* flagsA = (u32*)alloc((size_t)FA_WORDS_*4);    // 256 KB padded flags
  u32* flagsC = (u32*)alloc((size_t)FC_WORDS_*4);    // 128 KB
  size_t used = (size_t)(p - (char*)d_ws);

  // ---- chunked-Xz capacity: xf (21MB) + pool 2*CHA*B*G*2 (CHA MB) ----
  const size_t XFB = (size_t)S_*B_*EP_*2;
  const size_t CHUNK1 = (size_t)B_*G_*2;             // 0.5 MB per step per dir
  f16* xf = nullptr; f16* Xzf = nullptr; f16* Xzr = nullptr;
  int CHA = 0;
  for (int c = 256; c >= 16; c >>= 1){
    if (used + XFB + 2*(size_t)c*CHUNK1 + 1024 <= ws_size){ CHA = c; break; }
  }
  f16* Z1c; int CH;
  if (CHA){
    xf  = (f16*)alloc(XFB);
    Xzf = (f16*)alloc((size_t)CHA*CHUNK1);
    Xzr = (f16*)alloc((size_t)CHA*CHUNK1);
    // phaseC Z1c aliases the (contiguous, 256-aligned) Xzf+Xzr pool
    Z1c = Xzf;
    CH  = (2*CHA > 256) ? 256 : 2*CHA;
  } else {
    CH = 8;
    for (int c = 256; c >= 8; c >>= 1){
      if (used + (size_t)c*CHUNK1 <= ws_size){ CH = c; break; }
    }
    Z1c = (f16*)alloc((size_t)CH*CHUNK1);
  }
  const int NC = S_/CH;

  int n;
  n = G_*EP_; k_pad_w<<<(n+255)/256, 256, 0, stream>>>(wih0f, w0fp, G_, E_, EP_);
              k_pad_w<<<(n+255)/256, 256, 0, stream>>>(wih0r, w0rp, G_, E_, EP_);
  n = G_*H_;  k_f32_to_f16<<<(n+255)/256,256,0,stream>>>(whh0f, whf, n);
              k_f32_to_f16<<<(n+255)/256,256,0,stream>>>(whh0r, whr, n);
              k_f32_to_f16<<<(n+255)/256,256,0,stream>>>(whh1r, w1h, n);
  n = G_*D1_; k_f32_to_f16<<<(n+255)/256,256,0,stream>>>(wih1r, w1i, n);
  k_bias<<<8,256,0,stream>>>(bih0f, bhh0f, bs0, G_);
  k_bias<<<8,256,0,stream>>>(bih0r, bhh0r, bs0 + G_, G_);
  k_bias<<<8,256,0,stream>>>(bih1r, bhh1r, bs1r, G_);
  k_len<<<1,128,0,stream>>>(x, len);
  k_init<<<(B_*H_+255)/256,256,0,stream>>>(hxA, hx1, cstate, cstateA);
  k_zero<<<(FA_WORDS_+255)/256,256,0,stream>>>(flagsA, FA_WORDS_);
  k_zero<<<(FC_WORDS_+255)/256,256,0,stream>>>(flagsC, FC_WORDS_);
  k_fold<<<4,256,0,stream>>>(fc1w, fc1b, fcw, fcb, Mf, bf);

  // ---- phase A ----
  if (CHA){
    n = S_*B_*EP_;
    k_cast_x<<<(n+255)/256, 256, 0, stream>>>(x, xf);
    const int NCA = S_/CHA;
    for (int ca = 0; ca < NCA; ++ca){
      int s0  = ca*CHA;
      int t0f = s0;
      int t0r = S_ - CHA - s0;
      k_gemm_bt<<<dim3(CHA, G_/128), 256, 0, stream>>>(
          xf + (size_t)t0f*B_*EP_, w0fp, Xzf, bs0,      CHA*B_, G_, EP_);
      k_gemm_bt<<<dim3(CHA, G_/128), 256, 0, stream>>>(
          xf + (size_t)t0r*B_*EP_, w0rp, Xzr, bs0 + G_, CHA*B_, G_, EP_);
      k_phaseA_xz<<<dim3(2,32,2), 256, 0, stream>>>(
          Xzf, Xzr, whf, whr, len, hxA, cstateA, outcat, flagsA, s0, CHA);
    }
  } else {
    k_phaseA<<<dim3(2,32,2), 256, 0, stream>>>(
        x, w0fp, w0rp, whf, whr, bs0, len, hxA, outcat, flagsA);
  }

  // ---- phase C: per chunk, dense Z1 GEMM (128^2 tile) then recurrence ----
  for (int cc = 0; cc < NC; ++cc){
    int t0 = S_ - (cc+1)*CH;     // chunk covers t in [t0, t0+CH), consumed descending
    k_gemm_bt<<<dim3(CH, 16), 256, 0, stream>>>(
        outcat + (size_t)t0*B_*D1_, w1i, Z1c, bs1r, CH*B_, G_, D1_);
    k_phaseCrec<<<dim3(2,32), 256, 0, stream>>>(
        Z1c, w1h, len, hx1, cstate, h1f, flagsC, cc*CH, CH);
  }

  k_final<<<1,256,0,stream>>>(h1f, Mf, bf, out);
}